// Round 1
// 529.621 us; speedup vs baseline: 1.0610x; 1.0610x over previous
//
#include <hip/hip_runtime.h>

#define B_ 4
#define N_ 2048
#define D_ 2048

// ---- legacy 128^2 params (gemm_sym) ----
#define BM 128
#define BN 128
#define BK 32
#define TP 136   // mirror-tile pitch (ushorts): 272B rows -> every row 16B-aligned

typedef __bf16 bf16x8 __attribute__((ext_vector_type(8)));
typedef float  f32x4  __attribute__((ext_vector_type(4)));

__device__ __forceinline__ ushort f2bf(float x) {
  union { float f; unsigned u; } c; c.f = x;
  unsigned u = c.u;
  u += 0x7fffu + ((u >> 16) & 1u);   // RNE
  return (ushort)(u >> 16);
}

// async global->LDS, 16B per lane; lds base must be wave-uniform (HW adds lane*16)
__device__ __forceinline__ void gld16(ushort* lds, const ushort* g) {
  __builtin_amdgcn_global_load_lds(
      (const __attribute__((address_space(1))) void*)g,
      (__attribute__((address_space(3))) void*)lds, 16, 0, 0);
}

// ---------------- prep kernels ----------------

__global__ void prep_cn(const float* __restrict__ data, ushort* __restrict__ cn,
                        ushort* __restrict__ catA) {
  const int row = blockIdx.x;                 // 0..B*N-1
  const long base = (long)row * D_;
  const float4* r4 = (const float4*)(data + base);
  const int tid = threadIdx.x;                // 256 threads, 8 floats each
  float4 u0 = r4[tid * 2], u1 = r4[tid * 2 + 1];
  float s = u0.x*u0.x + u0.y*u0.y + u0.z*u0.z + u0.w*u0.w
          + u1.x*u1.x + u1.y*u1.y + u1.z*u1.z + u1.w*u1.w;
  #pragma unroll
  for (int o = 32; o > 0; o >>= 1) s += __shfl_down(s, o);
  __shared__ float wsum[4];
  if ((tid & 63) == 0) wsum[tid >> 6] = s;
  __syncthreads();
  const float tot = wsum[0] + wsum[1] + wsum[2] + wsum[3];
  const float sc = rsqrtf(fmaxf(tot, 1e-12f));
  uint4 pc, pd;
  pc.x = (unsigned)f2bf(u0.x * sc) | ((unsigned)f2bf(u0.y * sc) << 16);
  pc.y = (unsigned)f2bf(u0.z * sc) | ((unsigned)f2bf(u0.w * sc) << 16);
  pc.z = (unsigned)f2bf(u1.x * sc) | ((unsigned)f2bf(u1.y * sc) << 16);
  pc.w = (unsigned)f2bf(u1.z * sc) | ((unsigned)f2bf(u1.w * sc) << 16);
  pd.x = (unsigned)f2bf(u0.x) | ((unsigned)f2bf(u0.y) << 16);
  pd.y = (unsigned)f2bf(u0.z) | ((unsigned)f2bf(u0.w) << 16);
  pd.z = (unsigned)f2bf(u1.x) | ((unsigned)f2bf(u1.y) << 16);
  pd.w = (unsigned)f2bf(u1.z) | ((unsigned)f2bf(u1.w) << 16);
  *(uint4*)(cn + base + tid * 8) = pc;
  *(uint4*)(catA + (long)row * (2 * D_) + tid * 8) = pd;
}

__global__ void prep_pe(ushort* __restrict__ pe) {
  const int id = blockIdx.x * 256 + threadIdx.x;
  const int n = id >> 11, d = id & (D_ - 1);
  const float e = (float)(2 * (d >> 1)) * (1.0f / (float)D_);
  const float rate = expf(e * -9.210340371976184f);   // 10000^-e
  const float ang = (float)n * rate;
  const float v = (d & 1) ? cosf(ang) : sinf(ang);
  pe[id] = f2bf(v);
}

__global__ void transpose_bf16(const float* __restrict__ in, ushort* __restrict__ out,
                               int R, int C) {
  __shared__ float t[32][33];
  const int c0 = blockIdx.x * 32, r0 = blockIdx.y * 32;
  const int tx = threadIdx.x, ty = threadIdx.y;   // (32,8)
  #pragma unroll
  for (int i = 0; i < 32; i += 8) t[ty + i][tx] = in[(long)(r0 + ty + i) * C + c0 + tx];
  __syncthreads();
  #pragma unroll
  for (int i = 0; i < 32; i += 8) out[(long)(c0 + ty + i) * R + r0 + tx] = f2bf(t[tx][ty + i]);
}

// ---------------- G1: symmetric sim = relu(cn cn^T), triangular grid ----------------
__global__ __launch_bounds__(256, 2) void gemm_sym(
    const ushort* __restrict__ Ag, ushort* __restrict__ Cg, float* __restrict__ csum) {
  __shared__ ushort sAt[BM * BK];
  __shared__ ushort sBt[BN * BK];
  __shared__ ushort tile[128 * TP];   // transposed stash, 16B-aligned rows

  const int bz = blockIdx.z;
  const int t = blockIdx.x;
  int bj = (int)((sqrtf(8.f * (float)t + 1.f) - 1.f) * 0.5f);
  while ((bj + 1) * (bj + 2) / 2 <= t) bj++;
  while (bj * (bj + 1) / 2 > t) bj--;
  const int bi = t - bj * (bj + 1) / 2;

  const ushort* A = Ag + (long)bz * N_ * D_;
  const int blockRow = bi * BM;
  const int blockCol = bj * BN;

  const int tid = threadIdx.x;
  const int w = tid >> 6, L = tid & 63;
  const int ldRow = w * 16 + (L >> 2);
  const int ldK = (((L & 3) ^ ((L >> 3) & 3)) * 8);
  const ushort* a0 = A + (long)(blockRow + ldRow) * D_ + ldK;
  const ushort* a1 = a0 + (long)64 * D_;
  const ushort* b0 = A + (long)(blockCol + ldRow) * D_ + ldK;
  const ushort* b1 = b0 + (long)64 * D_;
  ushort* sA0 = sAt + w * 512;
  ushort* sA1 = sAt + 2048 + w * 512;
  ushort* sB0 = sBt + w * 512;
  ushort* sB1 = sBt + 2048 + w * 512;

  const int wm = (w & 1) * 64, wn = (w >> 1) * 64;
  const int fr = L & 15;
  const int sw = (((L >> 4) ^ ((fr >> 1) & 3)) * 8);

  f32x4 acc[4][4] = {};
  for (int k0 = 0; k0 < D_; k0 += BK) {
    gld16(sA0, a0); gld16(sA1, a1);
    gld16(sB0, b0); gld16(sB1, b1);
    a0 += BK; a1 += BK; b0 += BK; b1 += BK;
    __syncthreads();
    bf16x8 af[4], bfv[4];
    #pragma unroll
    for (int i = 0; i < 4; i++) af[i]  = *(const bf16x8*)&sAt[(wm + i * 16 + fr) * BK + sw];
    #pragma unroll
    for (int j = 0; j < 4; j++) bfv[j] = *(const bf16x8*)&sBt[(wn + j * 16 + fr) * BK + sw];
    #pragma unroll
    for (int i = 0; i < 4; i++)
      #pragma unroll
      for (int j = 0; j < 4; j++)
        acc[i][j] = __builtin_amdgcn_mfma_f32_16x16x32_bf16(af[i], bfv[j], acc[i][j], 0, 0, 0);
    __syncthreads();
  }

  const int rq = (L >> 4) * 4;   // C/D: row = rq + reg, col = L&15
  const int cq = L & 15;
  ushort* C = Cg + (long)bz * N_ * N_;

  float rs[4][4];
  float cs[4];
  #pragma unroll
  for (int i = 0; i < 4; i++)
    #pragma unroll
    for (int r = 0; r < 4; r++) rs[i][r] = 0.f;
  #pragma unroll
  for (int j = 0; j < 4; j++) cs[j] = 0.f;

  const bool offdiag = (bi != bj);
  #pragma unroll
  for (int i = 0; i < 4; i++)
    #pragma unroll
    for (int j = 0; j < 4; j++)
      #pragma unroll
      for (int r = 0; r < 4; r++) {
        const float v = fmaxf(acc[i][j][r], 0.f);
        const int lrow = wm + i * 16 + rq + r;
        const int lcol = wn + j * 16 + cq;
        const ushort bv = f2bf(v);
        C[(long)(blockRow + lrow) * N_ + blockCol + lcol] = bv;
        rs[i][r] += v;
        cs[j] += v;
        if (offdiag) tile[lcol * TP + lrow] = bv;
      }

  #pragma unroll
  for (int i = 0; i < 4; i++)
    #pragma unroll
    for (int r = 0; r < 4; r++) {
      float s = rs[i][r];
      s += __shfl_xor(s, 1); s += __shfl_xor(s, 2);
      s += __shfl_xor(s, 4); s += __shfl_xor(s, 8);
      if (cq == 0)
        atomicAdd(&csum[(long)bz * N_ + blockRow + wm + i * 16 + rq + r], s);
    }

  if (offdiag) {
    #pragma unroll
    for (int j = 0; j < 4; j++) {
      float s = cs[j];
      s += __shfl_xor(s, 16); s += __shfl_xor(s, 32);
      if (L < 16)
        atomicAdd(&csum[(long)bz * N_ + blockCol + wn + j * 16 + cq], s);
    }
    __syncthreads();
    const int rp = tid >> 1, h = tid & 1;
    const ushort* src = &tile[rp * TP + h * 64];
    ushort* dst = &C[(long)(blockCol + rp) * N_ + blockRow + h * 64];
    #pragma unroll
    for (int q = 0; q < 8; q++)
      *(uint4*)(dst + q * 8) = *(const uint4*)(src + q * 8);
  }
}

// ============ 256^2 8-phase NT GEMM (T2 swizzle + T3/T4 counted vmcnt + T5) ============
// BMx=BNx=256, BKx=64, 512 thr (8 waves, 2Mx4N), per-wave 128x64 out, 128KiB LDS dbuf.
// LDS swizzle: colByte ^= (row&7)<<4 (uniform over 32 banks for all ds_read_b128);
// applied on global src of global_load_lds (LDS linear) and on ds_read address.
// Per iter (2 K-tiles): ph1..4 compute buf0 tile, ph5..8 buf1 tile; stages:
//   ph2:B0(T+2) ph3:B1(T+2) ph4:A0+A1(T+2)+vmcnt(6) | ph6:B0(T+3) ph7:B1(T+3) ph8:A0+A1(T+3)+vmcnt(6)
// Every stage lands >=1 barrier after last read of its dest region (B read ph1/ph5 only;
// A rows ascending per phase, A staged at ph4/ph8 after its rows are consumed).
// Steady state: 3 half-tiles (6 loads) in flight -> vmcnt(6); never 0 in main loop.

__device__ __forceinline__ void stage_half(ushort* d, const ushort* s, int K) {
  gld16(d, s);
  gld16(d + 4096, s + (long)64 * K);
}

template <int M0, bool FIRST, class STG>
__device__ __forceinline__ void phase8(const ushort* __restrict__ TA,
                                       const ushort* __restrict__ TB,
                                       int aO0, int aO1, int bO0, int bO1,
                                       bf16x8 (&bf)[4][2], f32x4 (&acc)[8][4],
                                       int vm, STG&& stg) {
  if (FIRST) {
    #pragma unroll
    for (int j = 0; j < 4; j++) {
      bf[j][0] = *(const bf16x8*)&TB[bO0 + j * 1024];
      bf[j][1] = *(const bf16x8*)&TB[bO1 + j * 1024];
    }
  }
  bf16x8 af[2][2];
  #pragma unroll
  for (int mm = 0; mm < 2; mm++) {
    af[mm][0] = *(const bf16x8*)&TA[aO0 + (M0 + mm) * 1024];
    af[mm][1] = *(const bf16x8*)&TA[aO1 + (M0 + mm) * 1024];
  }
  __builtin_amdgcn_sched_barrier(0);   // reads issue before the prefetch
  stg();
  asm volatile("s_barrier" ::: "memory");
  asm volatile("s_waitcnt lgkmcnt(0)" ::: "memory");
  __builtin_amdgcn_sched_barrier(0);   // rule #18: keep MFMA below the wait
  __builtin_amdgcn_s_setprio(1);
  #pragma unroll
  for (int kk = 0; kk < 2; kk++)
    #pragma unroll
    for (int mm = 0; mm < 2; mm++)
      #pragma unroll
      for (int j = 0; j < 4; j++)
        acc[M0 + mm][j] = __builtin_amdgcn_mfma_f32_16x16x32_bf16(
            af[mm][kk], bf[j][kk], acc[M0 + mm][j], 0, 0, 0);
  __builtin_amdgcn_s_setprio(0);
  if (vm == 6)      asm volatile("s_waitcnt vmcnt(6)" ::: "memory");
  else if (vm == 0) asm volatile("s_waitcnt vmcnt(0)" ::: "memory");
  asm volatile("s_barrier" ::: "memory");
}

// MODE 1: bf16 store | MODE 2: softplus(acc + csum*w0 + bexp) bf16 at col+colOff | MODE 3: fp32
template <int MODE>
__global__ __launch_bounds__(512, 2) void gemm8(
    const ushort* __restrict__ Ag, const ushort* __restrict__ Bg, void* __restrict__ Cg,
    int K, long sA, long sB, long sC, int ldc, int colOff,
    const float* __restrict__ csum, const float* __restrict__ w0,
    const float* __restrict__ bexp) {
  extern __shared__ ushort lds[];   // [A0 16K | A1 16K | B0 16K | B1 16K] ushorts

  // XCD swizzle: lin%8 = "XCD" (round-robin assumption); each owns (z, y-half)
  const int lin = blockIdx.x + (blockIdx.y << 3) + (blockIdx.z << 6);
  const int xcd = lin & 7, m_ = lin >> 3;
  const int bz = xcd >> 1;
  const int by = ((xcd & 1) << 2) + (m_ >> 3);
  const int bx = m_ & 7;

  const ushort* A  = Ag + (long)bz * sA + (long)(bx << 8) * K;
  const ushort* Bp = Bg + (long)bz * sB + (long)(by << 8) * K;

  const int tid = threadIdx.x;
  // staging: thread covers linear half-tile bytes tid*16 (+8192 for q=1);
  // global col pre-swizzled so linear LDS holds swizzled layout
  const int sr = tid >> 3;                         // row within half (q=0)
  const int sc = ((tid & 7) ^ (sr & 7)) << 3;      // ushort col, XOR-swizzled
  const ushort* aS = A + (long)sr * K + sc;
  const ushort* bS = Bp + (long)sr * K + sc;
  const int wOff = (tid >> 6) << 9;                // wave-uniform LDS offset (ushorts)
  ushort* const stA0 = lds + wOff;
  ushort* const stA1 = lds + 16384 + wOff;
  ushort* const stB0 = lds + 32768 + wOff;
  ushort* const stB1 = lds + 49152 + wOff;
  const ushort* const TA0 = lds;          const ushort* const TA1 = lds + 16384;
  const ushort* const TB0 = lds + 32768;  const ushort* const TB1 = lds + 49152;

  auto stg = [&](ushort* base, const ushort* src, int T, int H) {
    stage_half(base + (H << 13), src + (long)(H << 7) * K + ((long)T << 6), K);
  };

  // fragment read offsets (swizzled)
  const int L = tid & 63, wid = tid >> 6;
  const int wr = wid >> 2, wc = wid & 3;
  const int fr = L & 15, g = L >> 4;
  const int off0 = ((g ^ (fr & 7)) << 3);
  const int aO0 = ((wr << 7) + fr) * 64 + off0, aO1 = aO0 ^ 32;
  const int bO0 = ((wc << 6) + fr) * 64 + off0, bO1 = bO0 ^ 32;

  f32x4 acc[8][4] = {};
  bf16x8 bf[4][2];

  const int NT = K >> 6, NTI = NT >> 1;

  // prologue: fully stage tiles 0 (buf0) and 1 (buf1); 16 issues
  stg(stB0, bS, 0, 0); stg(stB0, bS, 0, 1); stg(stA0, aS, 0, 0); stg(stA0, aS, 0, 1);
  stg(stB1, bS, 1, 0); stg(stB1, bS, 1, 1); stg(stA1, aS, 1, 0); stg(stA1, aS, 1, 1);
  asm volatile("s_waitcnt vmcnt(6)" ::: "memory");   // tile0 + B0(t1) landed
  asm volatile("s_barrier" ::: "memory");

  for (int it = 0; it < NTI; ++it) {
    const int T2 = 2 * it + 2;
    const bool more = (it + 1 < NTI);
    // tile 2it from buf0
    phase8<0, true >(TA0, TB0, aO0, aO1, bO0, bO1, bf, acc, -1, [&] {});
    phase8<2, false>(TA0, TB0, aO0, aO1, bO0, bO1, bf, acc, -1,
                     [&] { if (more) stg(stB0, bS, T2, 0); });
    phase8<4, false>(TA0, TB0, aO0, aO1, bO0, bO1, bf, acc, -1,
                     [&] { if (more) stg(stB0, bS, T2, 1); });
    phase8<6, false>(TA0, TB0, aO0, aO1, bO0, bO1, bf, acc, more ? 6 : 0,
                     [&] { if (more) { stg(stA0, aS, T2, 0); stg(stA0, aS, T2, 1); } });
    // tile 2it+1 from buf1
    phase8<0, true >(TA1, TB1, aO0, aO1, bO0, bO1, bf, acc, -1, [&] {});
    phase8<2, false>(TA1, TB1, aO0, aO1, bO0, bO1, bf, acc, -1,
                     [&] { if (more) stg(stB1, bS, T2 + 1, 0); });
    phase8<4, false>(TA1, TB1, aO0, aO1, bO0, bO1, bf, acc, -1,
                     [&] { if (more) stg(stB1, bS, T2 + 1, 1); });
    phase8<6, false>(TA1, TB1, aO0, aO1, bO0, bO1, bf, acc, more ? 6 : -1,
                     [&] { if (more) { stg(stA1, aS, T2 + 1, 0); stg(stA1, aS, T2 + 1, 1); } });
  }

  // epilogue
  const int rq = g << 2, cq = fr;
  const int rowB0 = (bx << 8) + (wr << 7);
  const int colB0 = (by << 8) + (wc << 6);
  if (MODE == 3) {
    float* C = (float*)Cg + (long)bz * sC;
    #pragma unroll
    for (int m = 0; m < 8; m++)
      #pragma unroll
      for (int j = 0; j < 4; j++)
        #pragma unroll
        for (int r = 0; r < 4; r++) {
          const int row = rowB0 + m * 16 + rq + r;
          const int col = colB0 + j * 16 + cq;
          C[(long)row * ldc + col] = acc[m][j][r];
        }
  } else {
    ushort* C = (ushort*)Cg + (long)bz * sC;
    #pragma unroll
    for (int m = 0; m < 8; m++)
      #pragma unroll
      for (int j = 0; j < 4; j++)
        #pragma unroll
        for (int r = 0; r < 4; r++) {
          const int row = rowB0 + m * 16 + rq + r;
          const int col = colB0 + j * 16 + cq;
          if (MODE == 1) {
            C[(long)row * ldc + col] = f2bf(acc[m][j][r]);
          } else {
            const float x = acc[m][j][r] + csum[(long)bz * N_ + row] * w0[col] + bexp[col];
            const float sp = fmaxf(x, 0.f) + log1pf(expf(-fabsf(x)));
            C[(long)row * ldc + colOff + col] = f2bf(sp);
          }
        }
  }
}

// ---------------- launch ----------------
extern "C" void kernel_launch(void* const* d_in, const int* in_sizes, int n_in,
                              void* d_out, int out_size, void* d_ws, size_t ws_size,
                              hipStream_t stream) {
  const float* data    = (const float*)d_in[0];
  const float* W_exp   = (const float*)d_in[1];
  const float* b_exp   = (const float*)d_in[2];
  const float* W_merge = (const float*)d_in[3];

  char* ws = (char*)d_ws;
  const size_t MB = 1024 * 1024;
  ushort* cnv  = (ushort*)(ws);             // 32MB: cn, then reused as v_out
  ushort* sim  = (ushort*)(ws + 32 * MB);   // 32MB
  ushort* pe   = (ushort*)(ws + 64 * MB);   // 8MB
  ushort* weT  = (ushort*)(ws + 72 * MB);   // 8MB:  W_exp[1:,:]^T
  ushort* wmT  = (ushort*)(ws + 80 * MB);   // 16MB: W_merge^T
  ushort* catA = (ushort*)(ws + 96 * MB);   // 64MB: [data | counter] bf16
  float*  csum = (float*)(ws + 160 * MB);   // 128KB

  static bool attrs_set = false;
  if (!attrs_set) {
    hipFuncSetAttribute((const void*)gemm8<1>, hipFuncAttributeMaxDynamicSharedMemorySize, 131072);
    hipFuncSetAttribute((const void*)gemm8<2>, hipFuncAttributeMaxDynamicSharedMemorySize, 131072);
    hipFuncSetAttribute((const void*)gemm8<3>, hipFuncAttributeMaxDynamicSharedMemorySize, 131072);
    attrs_set = true;
  }

  hipMemsetAsync(csum, 0, (size_t)B_ * N_ * sizeof(float), stream);
  prep_cn<<<B_ * N_, 256, 0, stream>>>(data, cnv, catA);
  prep_pe<<<(N_ * N_) / 256, 256, 0, stream>>>(pe);
  transpose_bf16<<<dim3(D_ / 32, D_ / 32), dim3(32, 8), 0, stream>>>(W_exp + D_, weT, D_, D_);
  transpose_bf16<<<dim3(D_ / 32, (2 * D_) / 32), dim3(32, 8), 0, stream>>>(W_merge, wmT, 2 * D_, D_);

  // G1: sim = relu(cn cn^T) symmetric-triangular, csum row+col sums
  gemm_sym<<<dim3(136, 1, B_), dim3(256), 0, stream>>>(cnv, sim, csum);

  dim3 g8(N_ / 256, N_ / 256, B_);
  // G2: v_out = pe @ sim  (sim symmetric -> NT form), into cnv region (cn is dead)
  gemm8<1><<<g8, 512, 131072, stream>>>(pe, sim, cnv, N_, 0, (long)N_ * N_,
                                        (long)N_ * N_, N_, 0, nullptr, nullptr, nullptr);
  // G3: catA[:, D:] = softplus(v_out @ W_exp[1:] + csum*w0 + b_exp)
  gemm8<2><<<g8, 512, 131072, stream>>>(cnv, weT, catA, N_, (long)N_ * N_, 0,
                                        (long)N_ * 2 * D_, 2 * D_, D_, csum, W_exp, b_exp);
  // G4: out = catA @ W_merge
  gemm8<3><<<g8, 512, 131072, stream>>>(catA, wmT, d_out, 2 * D_, (long)N_ * 2 * D_, 0,
                                        (long)N_ * D_, D_, 0, nullptr, nullptr, nullptr);
}

// Round 3
// 508.026 us; speedup vs baseline: 1.1061x; 1.0425x over previous
//
#include <hip/hip_runtime.h>

#define B_ 4
#define N_ 2048
#define D_ 2048

// ---- legacy 128^2 params (gemm_sym) ----
#define BM 128
#define BN 128
#define BK 32
#define TP 136   // mirror-tile pitch (ushorts): 272B rows -> every row 16B-aligned

typedef __bf16 bf16x8 __attribute__((ext_vector_type(8)));
typedef float  f32x4  __attribute__((ext_vector_type(4)));

__device__ __forceinline__ ushort f2bf(float x) {
  union { float f; unsigned u; } c; c.f = x;
  unsigned u = c.u;
  u += 0x7fffu + ((u >> 16) & 1u);   // RNE
  return (ushort)(u >> 16);
}

// async global->LDS, 16B per lane; lds base must be wave-uniform (HW adds lane*16)
__device__ __forceinline__ void gld16(ushort* lds, const ushort* g) {
  __builtin_amdgcn_global_load_lds(
      (const __attribute__((address_space(1))) void*)g,
      (__attribute__((address_space(3))) void*)lds, 16, 0, 0);
}

// ---------------- prep kernels ----------------

__global__ void prep_cn(const float* __restrict__ data, ushort* __restrict__ cn,
                        ushort* __restrict__ catA) {
  const int row = blockIdx.x;                 // 0..B*N-1
  const long base = (long)row * D_;
  const float4* r4 = (const float4*)(data + base);
  const int tid = threadIdx.x;                // 256 threads, 8 floats each
  float4 u0 = r4[tid * 2], u1 = r4[tid * 2 + 1];
  float s = u0.x*u0.x + u0.y*u0.y + u0.z*u0.z + u0.w*u0.w
          + u1.x*u1.x + u1.y*u1.y + u1.z*u1.z + u1.w*u1.w;
  #pragma unroll
  for (int o = 32; o > 0; o >>= 1) s += __shfl_down(s, o);
  __shared__ float wsum[4];
  if ((tid & 63) == 0) wsum[tid >> 6] = s;
  __syncthreads();
  const float tot = wsum[0] + wsum[1] + wsum[2] + wsum[3];
  const float sc = rsqrtf(fmaxf(tot, 1e-12f));
  uint4 pc, pd;
  pc.x = (unsigned)f2bf(u0.x * sc) | ((unsigned)f2bf(u0.y * sc) << 16);
  pc.y = (unsigned)f2bf(u0.z * sc) | ((unsigned)f2bf(u0.w * sc) << 16);
  pc.z = (unsigned)f2bf(u1.x * sc) | ((unsigned)f2bf(u1.y * sc) << 16);
  pc.w = (unsigned)f2bf(u1.z * sc) | ((unsigned)f2bf(u1.w * sc) << 16);
  pd.x = (unsigned)f2bf(u0.x) | ((unsigned)f2bf(u0.y) << 16);
  pd.y = (unsigned)f2bf(u0.z) | ((unsigned)f2bf(u0.w) << 16);
  pd.z = (unsigned)f2bf(u1.x) | ((unsigned)f2bf(u1.y) << 16);
  pd.w = (unsigned)f2bf(u1.z) | ((unsigned)f2bf(u1.w) << 16);
  *(uint4*)(cn + base + tid * 8) = pc;
  *(uint4*)(catA + (long)row * (2 * D_) + tid * 8) = pd;
}

__global__ void prep_pe(ushort* __restrict__ pe) {
  const int id = blockIdx.x * 256 + threadIdx.x;
  const int n = id >> 11, d = id & (D_ - 1);
  const float e = (float)(2 * (d >> 1)) * (1.0f / (float)D_);
  const float rate = expf(e * -9.210340371976184f);   // 10000^-e
  const float ang = (float)n * rate;
  const float v = (d & 1) ? cosf(ang) : sinf(ang);
  pe[id] = f2bf(v);
}

__global__ void transpose_bf16(const float* __restrict__ in, ushort* __restrict__ out,
                               int R, int C) {
  __shared__ float t[32][33];
  const int c0 = blockIdx.x * 32, r0 = blockIdx.y * 32;
  const int tx = threadIdx.x, ty = threadIdx.y;   // (32,8)
  #pragma unroll
  for (int i = 0; i < 32; i += 8) t[ty + i][tx] = in[(long)(r0 + ty + i) * C + c0 + tx];
  __syncthreads();
  #pragma unroll
  for (int i = 0; i < 32; i += 8) out[(long)(c0 + ty + i) * R + r0 + tx] = f2bf(t[tx][ty + i]);
}

// ---------------- G1: symmetric sim = relu(cn cn^T), triangular grid ----------------
// Direct tile AND mirrored tile are both staged through LDS -> uint4 full-line stores.
__global__ __launch_bounds__(256, 2) void gemm_sym(
    const ushort* __restrict__ Ag, ushort* __restrict__ Cg, float* __restrict__ csum) {
  __shared__ ushort sAt[BM * BK];
  __shared__ ushort sBt[BN * BK];
  __shared__ ushort tile[128 * TP];   // stash, 16B-aligned rows

  const int bz = blockIdx.z;
  const int t = blockIdx.x;
  int bj = (int)((sqrtf(8.f * (float)t + 1.f) - 1.f) * 0.5f);
  while ((bj + 1) * (bj + 2) / 2 <= t) bj++;
  while (bj * (bj + 1) / 2 > t) bj--;
  const int bi = t - bj * (bj + 1) / 2;

  const ushort* A = Ag + (long)bz * N_ * D_;
  const int blockRow = bi * BM;
  const int blockCol = bj * BN;

  const int tid = threadIdx.x;
  const int w = tid >> 6, L = tid & 63;
  const int ldRow = w * 16 + (L >> 2);
  const int ldK = (((L & 3) ^ ((L >> 3) & 3)) * 8);
  const ushort* a0 = A + (long)(blockRow + ldRow) * D_ + ldK;
  const ushort* a1 = a0 + (long)64 * D_;
  const ushort* b0 = A + (long)(blockCol + ldRow) * D_ + ldK;
  const ushort* b1 = b0 + (long)64 * D_;
  ushort* sA0 = sAt + w * 512;
  ushort* sA1 = sAt + 2048 + w * 512;
  ushort* sB0 = sBt + w * 512;
  ushort* sB1 = sBt + 2048 + w * 512;

  const int wm = (w & 1) * 64, wn = (w >> 1) * 64;
  const int fr = L & 15;
  const int sw = (((L >> 4) ^ ((fr >> 1) & 3)) * 8);

  f32x4 acc[4][4] = {};
  for (int k0 = 0; k0 < D_; k0 += BK) {
    gld16(sA0, a0); gld16(sA1, a1);
    gld16(sB0, b0); gld16(sB1, b1);
    a0 += BK; a1 += BK; b0 += BK; b1 += BK;
    __syncthreads();
    bf16x8 af[4], bfv[4];
    #pragma unroll
    for (int i = 0; i < 4; i++) af[i]  = *(const bf16x8*)&sAt[(wm + i * 16 + fr) * BK + sw];
    #pragma unroll
    for (int j = 0; j < 4; j++) bfv[j] = *(const bf16x8*)&sBt[(wn + j * 16 + fr) * BK + sw];
    #pragma unroll
    for (int i = 0; i < 4; i++)
      #pragma unroll
      for (int j = 0; j < 4; j++)
        acc[i][j] = __builtin_amdgcn_mfma_f32_16x16x32_bf16(af[i], bfv[j], acc[i][j], 0, 0, 0);
    __syncthreads();
  }

  const int rq = (L >> 4) * 4;   // C/D: row = rq + reg, col = L&15
  const int cq = L & 15;
  ushort* C = Cg + (long)bz * N_ * N_;

  float rs[4][4];
  float cs[4];
  #pragma unroll
  for (int i = 0; i < 4; i++)
    #pragma unroll
    for (int r = 0; r < 4; r++) rs[i][r] = 0.f;
  #pragma unroll
  for (int j = 0; j < 4; j++) cs[j] = 0.f;

  const bool offdiag = (bi != bj);

  // pass 1: direct-layout stash + sums
  #pragma unroll
  for (int i = 0; i < 4; i++)
    #pragma unroll
    for (int j = 0; j < 4; j++)
      #pragma unroll
      for (int r = 0; r < 4; r++) {
        const float v = fmaxf(acc[i][j][r], 0.f);
        rs[i][r] += v;
        cs[j] += v;
        tile[(wm + i * 16 + rq + r) * TP + wn + j * 16 + cq] = f2bf(v);
      }
  __syncthreads();
  {
    const int rp = tid >> 1, h = tid & 1;
    const ushort* src = &tile[rp * TP + h * 64];
    ushort* dst = &C[(long)(blockRow + rp) * N_ + blockCol + h * 64];
    #pragma unroll
    for (int q = 0; q < 8; q++)
      *(uint4*)(dst + q * 8) = *(const uint4*)(src + q * 8);
  }

  // row sums -> csum[bi range]
  #pragma unroll
  for (int i = 0; i < 4; i++)
    #pragma unroll
    for (int r = 0; r < 4; r++) {
      float s = rs[i][r];
      s += __shfl_xor(s, 1); s += __shfl_xor(s, 2);
      s += __shfl_xor(s, 4); s += __shfl_xor(s, 8);
      if (cq == 0)
        atomicAdd(&csum[(long)bz * N_ + blockRow + wm + i * 16 + rq + r], s);
    }

  if (offdiag) {
    // col sums (== row sums of mirrored tile) -> csum[bj range]
    #pragma unroll
    for (int j = 0; j < 4; j++) {
      float s = cs[j];
      s += __shfl_xor(s, 16); s += __shfl_xor(s, 32);
      if (L < 16)
        atomicAdd(&csum[(long)bz * N_ + blockCol + wn + j * 16 + cq], s);
    }
    __syncthreads();   // direct copy done -> safe to refill transposed
    #pragma unroll
    for (int i = 0; i < 4; i++)
      #pragma unroll
      for (int j = 0; j < 4; j++)
        #pragma unroll
        for (int r = 0; r < 4; r++) {
          const float v = fmaxf(acc[i][j][r], 0.f);
          tile[(wn + j * 16 + cq) * TP + wm + i * 16 + rq + r] = f2bf(v);
        }
    __syncthreads();   // transposed stash complete
    const int rp = tid >> 1, h = tid & 1;
    const ushort* src = &tile[rp * TP + h * 64];
    ushort* dst = &C[(long)(blockCol + rp) * N_ + blockRow + h * 64];
    #pragma unroll
    for (int q = 0; q < 8; q++)
      *(uint4*)(dst + q * 8) = *(const uint4*)(src + q * 8);
  }
}

// ============ 256^2 8-phase NT GEMM (T2 swizzle + T3/T4 counted vmcnt + T5) ============
// Main loop unchanged from R1 (schedule verified). Epilogue LDS-staged + vectorized:
// per wave, per 16-row m-step: scalar writes into a private padded LDS patch (intra-wave
// DS ordering, no barriers), then full-cache-line uint4/f32x4 stores to global.

__device__ __forceinline__ void stage_half(ushort* d, const ushort* s, int K) {
  gld16(d, s);
  gld16(d + 4096, s + (long)64 * K);
}

template <int M0, bool FIRST, class STG>
__device__ __forceinline__ void phase8(const ushort* __restrict__ TA,
                                       const ushort* __restrict__ TB,
                                       int aO0, int aO1, int bO0, int bO1,
                                       bf16x8 (&bf)[4][2], f32x4 (&acc)[8][4],
                                       int vm, STG&& stg) {
  if (FIRST) {
    #pragma unroll
    for (int j = 0; j < 4; j++) {
      bf[j][0] = *(const bf16x8*)&TB[bO0 + j * 1024];
      bf[j][1] = *(const bf16x8*)&TB[bO1 + j * 1024];
    }
  }
  bf16x8 af[2][2];
  #pragma unroll
  for (int mm = 0; mm < 2; mm++) {
    af[mm][0] = *(const bf16x8*)&TA[aO0 + (M0 + mm) * 1024];
    af[mm][1] = *(const bf16x8*)&TA[aO1 + (M0 + mm) * 1024];
  }
  __builtin_amdgcn_sched_barrier(0);   // reads issue before the prefetch
  stg();
  asm volatile("s_barrier" ::: "memory");
  asm volatile("s_waitcnt lgkmcnt(0)" ::: "memory");
  __builtin_amdgcn_sched_barrier(0);   // rule #18: keep MFMA below the wait
  __builtin_amdgcn_s_setprio(1);
  #pragma unroll
  for (int kk = 0; kk < 2; kk++)
    #pragma unroll
    for (int mm = 0; mm < 2; mm++)
      #pragma unroll
      for (int j = 0; j < 4; j++)
        acc[M0 + mm][j] = __builtin_amdgcn_mfma_f32_16x16x32_bf16(
            af[mm][kk], bf[j][kk], acc[M0 + mm][j], 0, 0, 0);
  __builtin_amdgcn_s_setprio(0);
  if (vm == 6)      asm volatile("s_waitcnt vmcnt(6)" ::: "memory");
  else if (vm == 0) asm volatile("s_waitcnt vmcnt(0)" ::: "memory");
  asm volatile("s_barrier" ::: "memory");
}

// MODE 1: bf16 store | MODE 2: softplus(acc + csum*w0 + bexp) bf16 at col+colOff | MODE 3: fp32
template <int MODE>
__global__ __launch_bounds__(512, 2) void gemm8(
    const ushort* __restrict__ Ag, const ushort* __restrict__ Bg, void* __restrict__ Cg,
    int K, long sA, long sB, long sC, int ldc, int colOff,
    const float* __restrict__ csum, const float* __restrict__ w0,
    const float* __restrict__ bexp) {
  extern __shared__ ushort lds[];   // [A0 16K | A1 16K | B0 16K | B1 16K] ushorts

  // XCD swizzle: lin%8 = "XCD" (round-robin assumption); each owns (z, y-half)
  const int lin = blockIdx.x + (blockIdx.y << 3) + (blockIdx.z << 6);
  const int xcd = lin & 7, m_ = lin >> 3;
  const int bz = xcd >> 1;
  const int by = ((xcd & 1) << 2) + (m_ >> 3);
  const int bx = m_ & 7;

  const ushort* A  = Ag + (long)bz * sA + (long)(bx << 8) * K;
  const ushort* Bp = Bg + (long)bz * sB + (long)(by << 8) * K;

  const int tid = threadIdx.x;
  // staging: thread covers linear half-tile bytes tid*16 (+8192 for q=1);
  // global col pre-swizzled so linear LDS holds swizzled layout
  const int sr = tid >> 3;                         // row within half (q=0)
  const int sc = ((tid & 7) ^ (sr & 7)) << 3;      // ushort col, XOR-swizzled
  const ushort* aS = A + (long)sr * K + sc;
  const ushort* bS = Bp + (long)sr * K + sc;
  const int wOff = (tid >> 6) << 9;                // wave-uniform LDS offset (ushorts)
  ushort* const stA0 = lds + wOff;
  ushort* const stA1 = lds + 16384 + wOff;
  ushort* const stB0 = lds + 32768 + wOff;
  ushort* const stB1 = lds + 49152 + wOff;
  const ushort* const TA0 = lds;          const ushort* const TA1 = lds + 16384;
  const ushort* const TB0 = lds + 32768;  const ushort* const TB1 = lds + 49152;

  auto stg = [&](ushort* base, const ushort* src, int T, int H) {
    stage_half(base + (H << 13), src + (long)(H << 7) * K + ((long)T << 6), K);
  };

  // fragment read offsets (swizzled)
  const int L = tid & 63, wid = tid >> 6;
  const int wr = wid >> 2, wc = wid & 3;
  const int fr = L & 15, g = L >> 4;
  const int off0 = ((g ^ (fr & 7)) << 3);
  const int aO0 = ((wr << 7) + fr) * 64 + off0, aO1 = aO0 ^ 32;
  const int bO0 = ((wc << 6) + fr) * 64 + off0, bO1 = bO0 ^ 32;

  f32x4 acc[8][4] = {};
  bf16x8 bf[4][2];

  const int NT = K >> 6, NTI = NT >> 1;

  // prologue: fully stage tiles 0 (buf0) and 1 (buf1); 16 issues
  stg(stB0, bS, 0, 0); stg(stB0, bS, 0, 1); stg(stA0, aS, 0, 0); stg(stA0, aS, 0, 1);
  stg(stB1, bS, 1, 0); stg(stB1, bS, 1, 1); stg(stA1, aS, 1, 0); stg(stA1, aS, 1, 1);
  asm volatile("s_waitcnt vmcnt(6)" ::: "memory");   // tile0 + B0(t1) landed
  asm volatile("s_barrier" ::: "memory");

  for (int it = 0; it < NTI; ++it) {
    const int T2 = 2 * it + 2;
    const bool more = (it + 1 < NTI);
    // tile 2it from buf0
    phase8<0, true >(TA0, TB0, aO0, aO1, bO0, bO1, bf, acc, -1, [&] {});
    phase8<2, false>(TA0, TB0, aO0, aO1, bO0, bO1, bf, acc, -1,
                     [&] { if (more) stg(stB0, bS, T2, 0); });
    phase8<4, false>(TA0, TB0, aO0, aO1, bO0, bO1, bf, acc, -1,
                     [&] { if (more) stg(stB0, bS, T2, 1); });
    phase8<6, false>(TA0, TB0, aO0, aO1, bO0, bO1, bf, acc, more ? 6 : 0,
                     [&] { if (more) { stg(stA0, aS, T2, 0); stg(stA0, aS, T2, 1); } });
    // tile 2it+1 from buf1
    phase8<0, true >(TA1, TB1, aO0, aO1, bO0, bO1, bf, acc, -1, [&] {});
    phase8<2, false>(TA1, TB1, aO0, aO1, bO0, bO1, bf, acc, -1,
                     [&] { if (more) stg(stB1, bS, T2 + 1, 0); });
    phase8<4, false>(TA1, TB1, aO0, aO1, bO0, bO1, bf, acc, -1,
                     [&] { if (more) stg(stB1, bS, T2 + 1, 1); });
    phase8<6, false>(TA1, TB1, aO0, aO1, bO0, bO1, bf, acc, more ? 6 : -1,
                     [&] { if (more) { stg(stA1, aS, T2 + 1, 0); stg(stA1, aS, T2 + 1, 1); } });
  }

  // ---------------- vectorized epilogue (per-wave private LDS patch) ----------------
  // Last phase ended with s_barrier: all waves done reading stage buffers -> LDS free.
  const int cq = fr;                      // fragment col within 16x16 quad
  const int rowB0 = (bx << 8) + (wr << 7);
  const int colB0 = (by << 8) + (wc << 6);

  if (MODE == 3) {
    // per-wave 16x64 fp32 patch, pitch 68 floats (272B rows, 16B-aligned)
    float* eT = (float*)lds + (size_t)wid * 1088;
    float* Cb = (float*)Cg + (long)bz * sC;
    const int er = L >> 4, ec = L & 15;
    #pragma unroll
    for (int m = 0; m < 8; m++) {
      #pragma unroll
      for (int j = 0; j < 4; j++)
        #pragma unroll
        for (int r = 0; r < 4; r++)
          eT[(g * 4 + r) * 68 + j * 16 + cq] = acc[m][j][r];
      #pragma unroll
      for (int q = 0; q < 4; q++) {
        const f32x4 v = *(const f32x4*)&eT[(er + q * 4) * 68 + ec * 4];
        const long row = rowB0 + m * 16 + er + q * 4;
        *(f32x4*)&Cb[row * ldc + colB0 + ec * 4] = v;   // 16 lanes x 16B = 256B/row
      }
    }
  } else {
    // per-wave 16x64 bf16 patch, pitch 72 ushorts (144B rows, 16B-aligned)
    ushort* eT = lds + (size_t)wid * 1152;
    ushort* Cb = (ushort*)Cg + (long)bz * sC;
    const int er = L >> 3, ec = L & 7;
    float w0v[4], bev[4];
    if (MODE == 2) {
      #pragma unroll
      for (int j = 0; j < 4; j++) {
        w0v[j] = w0[colB0 + j * 16 + cq];
        bev[j] = bexp[colB0 + j * 16 + cq];
      }
    }
    #pragma unroll
    for (int m = 0; m < 8; m++) {
      #pragma unroll
      for (int j = 0; j < 4; j++)
        #pragma unroll
        for (int r = 0; r < 4; r++) {
          float x = acc[m][j][r];
          if (MODE == 2) {
            const float cv = csum[(long)bz * N_ + rowB0 + m * 16 + g * 4 + r];
            x = x + cv * w0v[j] + bev[j];
            x = fmaxf(x, 0.f) + log1pf(expf(-fabsf(x)));
          }
          eT[(g * 4 + r) * 72 + j * 16 + cq] = f2bf(x);
        }
      #pragma unroll
      for (int q = 0; q < 2; q++) {
        const uint4 v = *(const uint4*)&eT[(er + q * 8) * 72 + ec * 8];
        const long row = rowB0 + m * 16 + er + q * 8;
        *(uint4*)&Cb[row * ldc + colOff + colB0 + ec * 8] = v;  // 8 lanes x 16B = 128B/row
      }
    }
  }
}

// ---------------- launch ----------------
extern "C" void kernel_launch(void* const* d_in, const int* in_sizes, int n_in,
                              void* d_out, int out_size, void* d_ws, size_t ws_size,
                              hipStream_t stream) {
  const float* data    = (const float*)d_in[0];
  const float* W_exp   = (const float*)d_in[1];
  const float* b_exp   = (const float*)d_in[2];
  const float* W_merge = (const float*)d_in[3];

  char* ws = (char*)d_ws;
  const size_t MB = 1024 * 1024;
  ushort* cnv  = (ushort*)(ws);             // 32MB: cn, then reused as v_out
  ushort* sim  = (ushort*)(ws + 32 * MB);   // 32MB
  ushort* pe   = (ushort*)(ws + 64 * MB);   // 8MB
  ushort* weT  = (ushort*)(ws + 72 * MB);   // 8MB:  W_exp[1:,:]^T
  ushort* wmT  = (ushort*)(ws + 80 * MB);   // 16MB: W_merge^T
  ushort* catA = (ushort*)(ws + 96 * MB);   // 64MB: [data | counter] bf16
  float*  csum = (float*)(ws + 160 * MB);   // 128KB

  static bool attrs_set = false;
  if (!attrs_set) {
    (void)hipFuncSetAttribute((const void*)gemm8<1>, hipFuncAttributeMaxDynamicSharedMemorySize, 131072);
    (void)hipFuncSetAttribute((const void*)gemm8<2>, hipFuncAttributeMaxDynamicSharedMemorySize, 131072);
    (void)hipFuncSetAttribute((const void*)gemm8<3>, hipFuncAttributeMaxDynamicSharedMemorySize, 131072);
    attrs_set = true;
  }

  hipMemsetAsync(csum, 0, (size_t)B_ * N_ * sizeof(float), stream);
  prep_cn<<<B_ * N_, 256, 0, stream>>>(data, cnv, catA);
  prep_pe<<<(N_ * N_) / 256, 256, 0, stream>>>(pe);
  transpose_bf16<<<dim3(D_ / 32, D_ / 32), dim3(32, 8), 0, stream>>>(W_exp + D_, weT, D_, D_);
  transpose_bf16<<<dim3(D_ / 32, (2 * D_) / 32), dim3(32, 8), 0, stream>>>(W_merge, wmT, 2 * D_, D_);

  // G1: sim = relu(cn cn^T) symmetric-triangular, csum row+col sums
  gemm_sym<<<dim3(136, 1, B_), dim3(256), 0, stream>>>(cnv, sim, csum);

  dim3 g8(N_ / 256, N_ / 256, B_);
  // G2: v_out = pe @ sim  (sim symmetric -> NT form), into cnv region (cn is dead)
  gemm8<1><<<g8, 512, 131072, stream>>>(pe, sim, cnv, N_, 0, (long)N_ * N_,
                                        (long)N_ * N_, N_, 0, nullptr, nullptr, nullptr);
  // G3: catA[:, D:] = softplus(v_out @ W_exp[1:] + csum*w0 + b_exp)
  gemm8<2><<<g8, 512, 131072, stream>>>(cnv, weT, catA, N_, (long)N_ * N_, 0,
                                        (long)N_ * 2 * D_, 2 * D_, D_, csum, W_exp, b_exp);
  // G4: out = catA @ W_merge
  gemm8<3><<<g8, 512, 131072, stream>>>(catA, wmT, d_out, 2 * D_, (long)N_ * 2 * D_, 0,
                                        (long)N_ * D_, D_, 0, nullptr, nullptr, nullptr);
}

// Round 4
// 500.155 us; speedup vs baseline: 1.1235x; 1.0157x over previous
//
#include <hip/hip_runtime.h>

#define B_ 4
#define N_ 2048
#define D_ 2048

// ---- legacy 128^2 params (gemm_sym) ----
#define BM 128
#define BN 128
#define BK 32
#define TP 136   // mirror-tile pitch (ushorts): 272B rows -> every row 16B-aligned

typedef __bf16 bf16x8 __attribute__((ext_vector_type(8)));
typedef float  f32x4  __attribute__((ext_vector_type(4)));

__device__ __forceinline__ ushort f2bf(float x) {
  union { float f; unsigned u; } c; c.f = x;
  unsigned u = c.u;
  u += 0x7fffu + ((u >> 16) & 1u);   // RNE
  return (ushort)(u >> 16);
}

// async global->LDS, 16B per lane; lds base must be wave-uniform (HW adds lane*16)
__device__ __forceinline__ void gld16(ushort* lds, const ushort* g) {
  __builtin_amdgcn_global_load_lds(
      (const __attribute__((address_space(1))) void*)g,
      (__attribute__((address_space(3))) void*)lds, 16, 0, 0);
}

// ---------------- prep kernels ----------------

__global__ void prep_cn(const float* __restrict__ data, ushort* __restrict__ cn,
                        ushort* __restrict__ catA) {
  const int row = blockIdx.x;                 // 0..B*N-1
  const long base = (long)row * D_;
  const float4* r4 = (const float4*)(data + base);
  const int tid = threadIdx.x;                // 256 threads, 8 floats each
  float4 u0 = r4[tid * 2], u1 = r4[tid * 2 + 1];
  float s = u0.x*u0.x + u0.y*u0.y + u0.z*u0.z + u0.w*u0.w
          + u1.x*u1.x + u1.y*u1.y + u1.z*u1.z + u1.w*u1.w;
  #pragma unroll
  for (int o = 32; o > 0; o >>= 1) s += __shfl_down(s, o);
  __shared__ float wsum[4];
  if ((tid & 63) == 0) wsum[tid >> 6] = s;
  __syncthreads();
  const float tot = wsum[0] + wsum[1] + wsum[2] + wsum[3];
  const float sc = rsqrtf(fmaxf(tot, 1e-12f));
  uint4 pc, pd;
  pc.x = (unsigned)f2bf(u0.x * sc) | ((unsigned)f2bf(u0.y * sc) << 16);
  pc.y = (unsigned)f2bf(u0.z * sc) | ((unsigned)f2bf(u0.w * sc) << 16);
  pc.z = (unsigned)f2bf(u1.x * sc) | ((unsigned)f2bf(u1.y * sc) << 16);
  pc.w = (unsigned)f2bf(u1.z * sc) | ((unsigned)f2bf(u1.w * sc) << 16);
  pd.x = (unsigned)f2bf(u0.x) | ((unsigned)f2bf(u0.y) << 16);
  pd.y = (unsigned)f2bf(u0.z) | ((unsigned)f2bf(u0.w) << 16);
  pd.z = (unsigned)f2bf(u1.x) | ((unsigned)f2bf(u1.y) << 16);
  pd.w = (unsigned)f2bf(u1.z) | ((unsigned)f2bf(u1.w) << 16);
  *(uint4*)(cn + base + tid * 8) = pc;
  *(uint4*)(catA + (long)row * (2 * D_) + tid * 8) = pd;
}

__global__ void prep_pe(ushort* __restrict__ pe) {
  const int id = blockIdx.x * 256 + threadIdx.x;
  const int n = id >> 11, d = id & (D_ - 1);
  const float e = (float)(2 * (d >> 1)) * (1.0f / (float)D_);
  const float rate = expf(e * -9.210340371976184f);   // 10000^-e
  const float ang = (float)n * rate;
  const float v = (d & 1) ? cosf(ang) : sinf(ang);
  pe[id] = f2bf(v);
}

__global__ void transpose_bf16(const float* __restrict__ in, ushort* __restrict__ out,
                               int R, int C) {
  __shared__ float t[32][33];
  const int c0 = blockIdx.x * 32, r0 = blockIdx.y * 32;
  const int tx = threadIdx.x, ty = threadIdx.y;   // (32,8)
  #pragma unroll
  for (int i = 0; i < 32; i += 8) t[ty + i][tx] = in[(long)(r0 + ty + i) * C + c0 + tx];
  __syncthreads();
  #pragma unroll
  for (int i = 0; i < 32; i += 8) out[(long)(c0 + ty + i) * R + r0 + tx] = f2bf(t[tx][ty + i]);
}

// ---------------- G1: symmetric sim = relu(cn cn^T), triangular grid ----------------
__global__ __launch_bounds__(256, 2) void gemm_sym(
    const ushort* __restrict__ Ag, ushort* __restrict__ Cg, float* __restrict__ csum) {
  __shared__ ushort sAt[BM * BK];
  __shared__ ushort sBt[BN * BK];
  __shared__ ushort tile[128 * TP];   // stash, 16B-aligned rows

  const int bz = blockIdx.z;
  const int t = blockIdx.x;
  int bj = (int)((sqrtf(8.f * (float)t + 1.f) - 1.f) * 0.5f);
  while ((bj + 1) * (bj + 2) / 2 <= t) bj++;
  while (bj * (bj + 1) / 2 > t) bj--;
  const int bi = t - bj * (bj + 1) / 2;

  const ushort* A = Ag + (long)bz * N_ * D_;
  const int blockRow = bi * BM;
  const int blockCol = bj * BN;

  const int tid = threadIdx.x;
  const int w = tid >> 6, L = tid & 63;
  const int ldRow = w * 16 + (L >> 2);
  const int ldK = (((L & 3) ^ ((L >> 3) & 3)) * 8);
  const ushort* a0 = A + (long)(blockRow + ldRow) * D_ + ldK;
  const ushort* a1 = a0 + (long)64 * D_;
  const ushort* b0 = A + (long)(blockCol + ldRow) * D_ + ldK;
  const ushort* b1 = b0 + (long)64 * D_;
  ushort* sA0 = sAt + w * 512;
  ushort* sA1 = sAt + 2048 + w * 512;
  ushort* sB0 = sBt + w * 512;
  ushort* sB1 = sBt + 2048 + w * 512;

  const int wm = (w & 1) * 64, wn = (w >> 1) * 64;
  const int fr = L & 15;
  const int sw = (((L >> 4) ^ ((fr >> 1) & 3)) * 8);

  f32x4 acc[4][4] = {};
  for (int k0 = 0; k0 < D_; k0 += BK) {
    gld16(sA0, a0); gld16(sA1, a1);
    gld16(sB0, b0); gld16(sB1, b1);
    a0 += BK; a1 += BK; b0 += BK; b1 += BK;
    __syncthreads();
    bf16x8 af[4], bfv[4];
    #pragma unroll
    for (int i = 0; i < 4; i++) af[i]  = *(const bf16x8*)&sAt[(wm + i * 16 + fr) * BK + sw];
    #pragma unroll
    for (int j = 0; j < 4; j++) bfv[j] = *(const bf16x8*)&sBt[(wn + j * 16 + fr) * BK + sw];
    #pragma unroll
    for (int i = 0; i < 4; i++)
      #pragma unroll
      for (int j = 0; j < 4; j++)
        acc[i][j] = __builtin_amdgcn_mfma_f32_16x16x32_bf16(af[i], bfv[j], acc[i][j], 0, 0, 0);
    __syncthreads();
  }

  const int rq = (L >> 4) * 4;   // C/D: row = rq + reg, col = L&15
  const int cq = L & 15;
  ushort* C = Cg + (long)bz * N_ * N_;

  float rs[4][4];
  float cs[4];
  #pragma unroll
  for (int i = 0; i < 4; i++)
    #pragma unroll
    for (int r = 0; r < 4; r++) rs[i][r] = 0.f;
  #pragma unroll
  for (int j = 0; j < 4; j++) cs[j] = 0.f;

  const bool offdiag = (bi != bj);

  // pass 1: direct-layout stash + sums
  #pragma unroll
  for (int i = 0; i < 4; i++)
    #pragma unroll
    for (int j = 0; j < 4; j++)
      #pragma unroll
      for (int r = 0; r < 4; r++) {
        const float v = fmaxf(acc[i][j][r], 0.f);
        rs[i][r] += v;
        cs[j] += v;
        tile[(wm + i * 16 + rq + r) * TP + wn + j * 16 + cq] = f2bf(v);
      }
  __syncthreads();
  {
    const int rp = tid >> 1, h = tid & 1;
    const ushort* src = &tile[rp * TP + h * 64];
    ushort* dst = &C[(long)(blockRow + rp) * N_ + blockCol + h * 64];
    #pragma unroll
    for (int q = 0; q < 8; q++)
      *(uint4*)(dst + q * 8) = *(const uint4*)(src + q * 8);
  }

  // row sums -> csum[bi range]
  #pragma unroll
  for (int i = 0; i < 4; i++)
    #pragma unroll
    for (int r = 0; r < 4; r++) {
      float s = rs[i][r];
      s += __shfl_xor(s, 1); s += __shfl_xor(s, 2);
      s += __shfl_xor(s, 4); s += __shfl_xor(s, 8);
      if (cq == 0)
        atomicAdd(&csum[(long)bz * N_ + blockRow + wm + i * 16 + rq + r], s);
    }

  if (offdiag) {
    #pragma unroll
    for (int j = 0; j < 4; j++) {
      float s = cs[j];
      s += __shfl_xor(s, 16); s += __shfl_xor(s, 32);
      if (L < 16)
        atomicAdd(&csum[(long)bz * N_ + blockCol + wn + j * 16 + cq], s);
    }
    __syncthreads();   // direct copy done -> safe to refill transposed
    #pragma unroll
    for (int i = 0; i < 4; i++)
      #pragma unroll
      for (int j = 0; j < 4; j++)
        #pragma unroll
        for (int r = 0; r < 4; r++) {
          const float v = fmaxf(acc[i][j][r], 0.f);
          tile[(wn + j * 16 + cq) * TP + wm + i * 16 + rq + r] = f2bf(v);
        }
    __syncthreads();   // transposed stash complete
    const int rp = tid >> 1, h = tid & 1;
    const ushort* src = &tile[rp * TP + h * 64];
    ushort* dst = &C[(long)(blockCol + rp) * N_ + blockRow + h * 64];
    #pragma unroll
    for (int q = 0; q < 8; q++)
      *(uint4*)(dst + q * 8) = *(const uint4*)(src + q * 8);
  }
}

// ============ 256^2 8-phase NT GEMM — read-hoisted schedule ============
// Each phase: {stage; lgkmcnt(0) [waits reads issued LAST phase]; [ph4/ph8: vmcnt+mid-barrier];
//              16 MFMA; issue NEXT phase's frag reads; s_barrier}
// LDS reads drain during other waves' MFMA + barrier wait -> MFMA no longer serialized
// behind the read stream. Stages re-placed so every stage is >=1 barrier after the
// target region's reads were lgkm-waited (stricter than the m201 template).
// Steady-state VMEM in flight: 6 -> 12 -> vmcnt(4) at ph4/ph8 (final iter: vmcnt(0)).

__device__ __forceinline__ void stage_half(ushort* d, const ushort* s, int K) {
  gld16(d, s);
  gld16(d + 4096, s + (long)64 * K);
}

template <int M0>
__device__ __forceinline__ void rd_a(const ushort* __restrict__ T, int aO0, int aO1,
                                     bf16x8 (&af)[2][2]) {
  af[0][0] = *(const bf16x8*)&T[aO0 + M0 * 1024];
  af[0][1] = *(const bf16x8*)&T[aO1 + M0 * 1024];
  af[1][0] = *(const bf16x8*)&T[aO0 + (M0 + 1) * 1024];
  af[1][1] = *(const bf16x8*)&T[aO1 + (M0 + 1) * 1024];
}

__device__ __forceinline__ void rd_b8(const ushort* __restrict__ T, int bO0, int bO1,
                                      bf16x8 (&bf)[4][2]) {
  #pragma unroll
  for (int j = 0; j < 4; j++) {
    bf[j][0] = *(const bf16x8*)&T[bO0 + j * 1024];
    bf[j][1] = *(const bf16x8*)&T[bO1 + j * 1024];
  }
}

template <int M0>
__device__ __forceinline__ void mfma16(const bf16x8 (&af)[2][2], const bf16x8 (&bf)[4][2],
                                       f32x4 (&acc)[8][4]) {
  #pragma unroll
  for (int kk = 0; kk < 2; kk++)
    #pragma unroll
    for (int mm = 0; mm < 2; mm++)
      #pragma unroll
      for (int j = 0; j < 4; j++)
        acc[M0 + mm][j] = __builtin_amdgcn_mfma_f32_16x16x32_bf16(
            af[mm][kk], bf[j][kk], acc[M0 + mm][j], 0, 0, 0);
}

#define W_LGKM0 asm volatile("s_waitcnt lgkmcnt(0)" ::: "memory")
#define W_VM4   asm volatile("s_waitcnt vmcnt(4)" ::: "memory")
#define W_VM0   asm volatile("s_waitcnt vmcnt(0)" ::: "memory")
#define SBAR    asm volatile("s_barrier" ::: "memory")
#define SCHB    __builtin_amdgcn_sched_barrier(0)
#define PRIO1   __builtin_amdgcn_s_setprio(1)
#define PRIO0   __builtin_amdgcn_s_setprio(0)

// MODE 1: bf16 store | MODE 2: softplus(acc + csum*w0 + bexp) bf16 at col+colOff | MODE 3: fp32
template <int MODE>
__global__ __launch_bounds__(512, 2) void gemm8(
    const ushort* __restrict__ Ag, const ushort* __restrict__ Bg, void* __restrict__ Cg,
    int K, long sA, long sB, long sC, int ldc, int colOff,
    const float* __restrict__ csum, const float* __restrict__ w0,
    const float* __restrict__ bexp) {
  extern __shared__ ushort lds[];   // [A0 16K | A1 16K | B0 16K | B1 16K] ushorts

  // XCD swizzle: lin%8 = "XCD" (round-robin assumption); each owns (z, y-half)
  const int lin = blockIdx.x + (blockIdx.y << 3) + (blockIdx.z << 6);
  const int xcd = lin & 7, m_ = lin >> 3;
  const int bz = xcd >> 1;
  const int by = ((xcd & 1) << 2) + (m_ >> 3);
  const int bx = m_ & 7;

  const ushort* A  = Ag + (long)bz * sA + (long)(bx << 8) * K;
  const ushort* Bp = Bg + (long)bz * sB + (long)(by << 8) * K;

  const int tid = threadIdx.x;
  // staging: thread covers linear half-tile bytes tid*16; global col pre-swizzled so
  // linear LDS holds the XOR-swizzled layout
  const int sr = tid >> 3;                         // row within half
  const int sc = ((tid & 7) ^ (sr & 7)) << 3;      // ushort col, XOR-swizzled
  const ushort* aS = A + (long)sr * K + sc;
  const ushort* bS = Bp + (long)sr * K + sc;
  const int wOff = (tid >> 6) << 9;                // wave-uniform LDS offset (ushorts)
  ushort* const stA0 = lds + wOff;
  ushort* const stA1 = lds + 16384 + wOff;
  ushort* const stB0 = lds + 32768 + wOff;
  ushort* const stB1 = lds + 49152 + wOff;
  const ushort* const TA0 = lds;          const ushort* const TA1 = lds + 16384;
  const ushort* const TB0 = lds + 32768;  const ushort* const TB1 = lds + 49152;

  auto stg = [&](ushort* base, const ushort* src, int T, int H) {
    stage_half(base + (H << 13), src + (long)(H << 7) * K + ((long)T << 6), K);
  };

  // fragment read offsets (swizzled)
  const int L = tid & 63, wid = tid >> 6;
  const int wr = wid >> 2, wc = wid & 3;
  const int fr = L & 15, g = L >> 4;
  const int off0 = ((g ^ (fr & 7)) << 3);
  const int aO0 = ((wr << 7) + fr) * 64 + off0, aO1 = aO0 ^ 32;
  const int bO0 = ((wc << 6) + fr) * 64 + off0, bO1 = bO0 ^ 32;

  f32x4 acc[8][4] = {};
  bf16x8 af[2][2], bf[4][2];

  const int NT = K >> 6, NTI = NT >> 1;

  // prologue: tile0 -> buf0 (8 loads), B(tile1) -> buf1 (4), A1h0(tile1) (2) = 14 issues
  stg(stB0, bS, 0, 0); stg(stB0, bS, 0, 1); stg(stA0, aS, 0, 0); stg(stA0, aS, 0, 1);
  stg(stB1, bS, 1, 0); stg(stB1, bS, 1, 1);
  stg(stA1, aS, 1, 0);
  asm volatile("s_waitcnt vmcnt(6)" ::: "memory");   // tile0 fully landed
  SBAR;
  // pre-reads for ph1 (B buf0 + A m0-1)
  rd_b8(TB0, bO0, bO1, bf);
  rd_a<0>(TA0, aO0, aO1, af);

  for (int it = 0; it < NTI; ++it) {
    const int t1 = 2 * it + 1, t2 = 2 * it + 2, t3 = 2 * it + 3;
    const bool more = (it + 1 < NTI);

    // ---- ph1: MFMA m0-1 (buf0) ----
    stg(stA1, aS, t1, 1);                 // A1h1(T1)
    W_LGKM0; SCHB;
    PRIO1; mfma16<0>(af, bf, acc); PRIO0; SCHB;
    rd_a<2>(TA0, aO0, aO1, af);
    SBAR;
    // ---- ph2: MFMA m2-3 ----
    if (more) stg(stB0, bS, t2, 0);       // B0h0(T2)
    W_LGKM0; SCHB;
    PRIO1; mfma16<2>(af, bf, acc); PRIO0; SCHB;
    rd_a<4>(TA0, aO0, aO1, af);
    SBAR;
    // ---- ph3: MFMA m4-5 ----
    if (more) stg(stB0, bS, t2, 1);       // B0h1(T2)
    W_LGKM0; SCHB;
    PRIO1; mfma16<4>(af, bf, acc); PRIO0; SCHB;
    rd_a<6>(TA0, aO0, aO1, af);
    SBAR;
    // ---- ph4: MFMA m6-7; then switch to buf1 reads ----
    W_LGKM0;
    if (more) { W_VM4; } else { W_VM0; }  // force tile T1 (buf1) landed
    SBAR;                                 // all waves' T1 slices visible
    SCHB;
    PRIO1; mfma16<6>(af, bf, acc); PRIO0; SCHB;
    rd_b8(TB1, bO0, bO1, bf);
    rd_a<0>(TA1, aO0, aO1, af);
    SBAR;
    // ---- ph5: MFMA m0-1 (buf1) ----
    if (more) stg(stA0, aS, t2, 0);       // A0h0(T2)
    W_LGKM0; SCHB;
    PRIO1; mfma16<0>(af, bf, acc); PRIO0; SCHB;
    rd_a<2>(TA1, aO0, aO1, af);
    SBAR;
    // ---- ph6: MFMA m2-3 ----
    if (more) stg(stA0, aS, t2, 1);       // A0h1(T2)
    W_LGKM0; SCHB;
    PRIO1; mfma16<2>(af, bf, acc); PRIO0; SCHB;
    rd_a<4>(TA1, aO0, aO1, af);
    SBAR;
    // ---- ph7: MFMA m4-5 ----
    if (more) stg(stB1, bS, t3, 0);       // B1h0(T3)
    W_LGKM0; SCHB;
    PRIO1; mfma16<4>(af, bf, acc); PRIO0; SCHB;
    rd_a<6>(TA1, aO0, aO1, af);
    SBAR;
    // ---- ph8: MFMA m6-7; then switch to buf0 (tile T2) reads ----
    if (more) stg(stB1, bS, t3, 1);       // B1h1(T3)
    W_LGKM0;
    if (more) { W_VM4; }                  // force tile T2 (buf0) landed
    SBAR;
    SCHB;
    PRIO1; mfma16<6>(af, bf, acc); PRIO0; SCHB;
    if (more) {
      rd_b8(TB0, bO0, bO1, bf);
      rd_a<0>(TA0, aO0, aO1, af);
      stg(stA1, aS, t3, 0);               // A1h0(T3) — extra lead for next iter's ph4
    }
    SBAR;
  }

  // ---------------- vectorized epilogue (per-wave private LDS patch) ----------------
  const int cq = fr;                      // fragment col within 16x16 quad
  const int rowB0 = (bx << 8) + (wr << 7);
  const int colB0 = (by << 8) + (wc << 6);

  if (MODE == 3) {
    // per-wave 16x64 fp32 patch, pitch 68 floats (272B rows, 16B-aligned)
    float* eT = (float*)lds + (size_t)wid * 1088;
    float* Cb = (float*)Cg + (long)bz * sC;
    const int er = L >> 4, ec = L & 15;
    #pragma unroll
    for (int m = 0; m < 8; m++) {
      #pragma unroll
      for (int j = 0; j < 4; j++)
        #pragma unroll
        for (int r = 0; r < 4; r++)
          eT[(g * 4 + r) * 68 + j * 16 + cq] = acc[m][j][r];
      #pragma unroll
      for (int q = 0; q < 4; q++) {
        const f32x4 v = *(const f32x4*)&eT[(er + q * 4) * 68 + ec * 4];
        const long row = rowB0 + m * 16 + er + q * 4;
        *(f32x4*)&Cb[row * ldc + colB0 + ec * 4] = v;   // 16 lanes x 16B = 256B/row
      }
    }
  } else {
    // per-wave 16x64 bf16 patch, pitch 72 ushorts (144B rows, 16B-aligned)
    ushort* eT = lds + (size_t)wid * 1152;
    ushort* Cb = (ushort*)Cg + (long)bz * sC;
    const int er = L >> 3, ec = L & 7;
    float w0v[4], bev[4];
    if (MODE == 2) {
      #pragma unroll
      for (int j = 0; j < 4; j++) {
        w0v[j] = w0[colB0 + j * 16 + cq];
        bev[j] = bexp[colB0 + j * 16 + cq];
      }
    }
    #pragma unroll
    for (int m = 0; m < 8; m++) {
      #pragma unroll
      for (int j = 0; j < 4; j++)
        #pragma unroll
        for (int r = 0; r < 4; r++) {
          float x = acc[m][j][r];
          if (MODE == 2) {
            const float cv = csum[(long)bz * N_ + rowB0 + m * 16 + g * 4 + r];
            x = x + cv * w0v[j] + bev[j];
            x = fmaxf(x, 0.f) + log1pf(expf(-fabsf(x)));
          }
          eT[(g * 4 + r) * 72 + j * 16 + cq] = f2bf(x);
        }
      #pragma unroll
      for (int q = 0; q < 2; q++) {
        const uint4 v = *(const uint4*)&eT[(er + q * 8) * 72 + ec * 8];
        const long row = rowB0 + m * 16 + er + q * 8;
        *(uint4*)&Cb[row * ldc + colOff + colB0 + ec * 8] = v;  // 8 lanes x 16B = 128B/row
      }
    }
  }
}

// ---------------- launch ----------------
extern "C" void kernel_launch(void* const* d_in, const int* in_sizes, int n_in,
                              void* d_out, int out_size, void* d_ws, size_t ws_size,
                              hipStream_t stream) {
  const float* data    = (const float*)d_in[0];
  const float* W_exp   = (const float*)d_in[1];
  const float* b_exp   = (const float*)d_in[2];
  const float* W_merge = (const float*)d_in[3];

  char* ws = (char*)d_ws;
  const size_t MB = 1024 * 1024;
  ushort* cnv  = (ushort*)(ws);             // 32MB: cn, then reused as v_out
  ushort* sim  = (ushort*)(ws + 32 * MB);   // 32MB
  ushort* pe   = (ushort*)(ws + 64 * MB);   // 8MB
  ushort* weT  = (ushort*)(ws + 72 * MB);   // 8MB:  W_exp[1:,:]^T
  ushort* wmT  = (ushort*)(ws + 80 * MB);   // 16MB: W_merge^T
  ushort* catA = (ushort*)(ws + 96 * MB);   // 64MB: [data | counter] bf16
  float*  csum = (float*)(ws + 160 * MB);   // 128KB

  static bool attrs_set = false;
  if (!attrs_set) {
    (void)hipFuncSetAttribute((const void*)gemm8<1>, hipFuncAttributeMaxDynamicSharedMemorySize, 131072);
    (void)hipFuncSetAttribute((const void*)gemm8<2>, hipFuncAttributeMaxDynamicSharedMemorySize, 131072);
    (void)hipFuncSetAttribute((const void*)gemm8<3>, hipFuncAttributeMaxDynamicSharedMemorySize, 131072);
    attrs_set = true;
  }

  hipMemsetAsync(csum, 0, (size_t)B_ * N_ * sizeof(float), stream);
  prep_cn<<<B_ * N_, 256, 0, stream>>>(data, cnv, catA);
  prep_pe<<<(N_ * N_) / 256, 256, 0, stream>>>(pe);
  transpose_bf16<<<dim3(D_ / 32, D_ / 32), dim3(32, 8), 0, stream>>>(W_exp + D_, weT, D_, D_);
  transpose_bf16<<<dim3(D_ / 32, (2 * D_) / 32), dim3(32, 8), 0, stream>>>(W_merge, wmT, 2 * D_, D_);

  // G1: sim = relu(cn cn^T) symmetric-triangular, csum row+col sums
  gemm_sym<<<dim3(136, 1, B_), dim3(256), 0, stream>>>(cnv, sim, csum);

  dim3 g8(N_ / 256, N_ / 256, B_);
  // G2: v_out = pe @ sim  (sim symmetric -> NT form), into cnv region (cn is dead)
  gemm8<1><<<g8, 512, 131072, stream>>>(pe, sim, cnv, N_, 0, (long)N_ * N_,
                                        (long)N_ * N_, N_, 0, nullptr, nullptr, nullptr);
  // G3: catA[:, D:] = softplus(v_out @ W_exp[1:] + csum*w0 + b_exp)
  gemm8<2><<<g8, 512, 131072, stream>>>(cnv, weT, catA, N_, (long)N_ * N_, 0,
                                        (long)N_ * 2 * D_, 2 * D_, D_, csum, W_exp, b_exp);
  // G4: out = catA @ W_merge
  gemm8<3><<<g8, 512, 131072, stream>>>(catA, wmT, d_out, 2 * D_, (long)N_ * 2 * D_, 0,
                                        (long)N_ * D_, D_, 0, nullptr, nullptr, nullptr);
}

// Round 5
// 490.730 us; speedup vs baseline: 1.1451x; 1.0192x over previous
//
#include <hip/hip_runtime.h>

#define B_ 4
#define N_ 2048
#define D_ 2048

typedef __bf16 bf16x8 __attribute__((ext_vector_type(8)));
typedef float  f32x4  __attribute__((ext_vector_type(4)));

__device__ __forceinline__ ushort f2bf(float x) {
  union { float f; unsigned u; } c; c.f = x;
  unsigned u = c.u;
  u += 0x7fffu + ((u >> 16) & 1u);   // RNE
  return (ushort)(u >> 16);
}

// async global->LDS, 16B per lane; lds base must be wave-uniform (HW adds lane*16)
__device__ __forceinline__ void gld16(ushort* lds, const ushort* g) {
  __builtin_amdgcn_global_load_lds(
      (const __attribute__((address_space(1))) void*)g,
      (__attribute__((address_space(3))) void*)lds, 16, 0, 0);
}

// ---------------- prep kernels ----------------

__global__ void prep_cn(const float* __restrict__ data, ushort* __restrict__ cn,
                        ushort* __restrict__ catA) {
  const int row = blockIdx.x;                 // 0..B*N-1
  const long base = (long)row * D_;
  const float4* r4 = (const float4*)(data + base);
  const int tid = threadIdx.x;                // 256 threads, 8 floats each
  float4 u0 = r4[tid * 2], u1 = r4[tid * 2 + 1];
  float s = u0.x*u0.x + u0.y*u0.y + u0.z*u0.z + u0.w*u0.w
          + u1.x*u1.x + u1.y*u1.y + u1.z*u1.z + u1.w*u1.w;
  #pragma unroll
  for (int o = 32; o > 0; o >>= 1) s += __shfl_down(s, o);
  __shared__ float wsum[4];
  if ((tid & 63) == 0) wsum[tid >> 6] = s;
  __syncthreads();
  const float tot = wsum[0] + wsum[1] + wsum[2] + wsum[3];
  const float sc = rsqrtf(fmaxf(tot, 1e-12f));
  uint4 pc, pd;
  pc.x = (unsigned)f2bf(u0.x * sc) | ((unsigned)f2bf(u0.y * sc) << 16);
  pc.y = (unsigned)f2bf(u0.z * sc) | ((unsigned)f2bf(u0.w * sc) << 16);
  pc.z = (unsigned)f2bf(u1.x * sc) | ((unsigned)f2bf(u1.y * sc) << 16);
  pc.w = (unsigned)f2bf(u1.z * sc) | ((unsigned)f2bf(u1.w * sc) << 16);
  pd.x = (unsigned)f2bf(u0.x) | ((unsigned)f2bf(u0.y) << 16);
  pd.y = (unsigned)f2bf(u0.z) | ((unsigned)f2bf(u0.w) << 16);
  pd.z = (unsigned)f2bf(u1.x) | ((unsigned)f2bf(u1.y) << 16);
  pd.w = (unsigned)f2bf(u1.z) | ((unsigned)f2bf(u1.w) << 16);
  *(uint4*)(cn + base + tid * 8) = pc;
  *(uint4*)(catA + (long)row * (2 * D_) + tid * 8) = pd;
}

__global__ void prep_pe(ushort* __restrict__ pe) {
  const int id = blockIdx.x * 256 + threadIdx.x;
  const int n = id >> 11, d = id & (D_ - 1);
  const float e = (float)(2 * (d >> 1)) * (1.0f / (float)D_);
  const float rate = expf(e * -9.210340371976184f);   // 10000^-e
  const float ang = (float)n * rate;
  const float v = (d & 1) ? cosf(ang) : sinf(ang);
  pe[id] = f2bf(v);
}

__global__ void transpose_bf16(const float* __restrict__ in, ushort* __restrict__ out,
                               int R, int C) {
  __shared__ float t[32][33];
  const int c0 = blockIdx.x * 32, r0 = blockIdx.y * 32;
  const int tx = threadIdx.x, ty = threadIdx.y;   // (32,8)
  #pragma unroll
  for (int i = 0; i < 32; i += 8) t[ty + i][tx] = in[(long)(r0 + ty + i) * C + c0 + tx];
  __syncthreads();
  #pragma unroll
  for (int i = 0; i < 32; i += 8) out[(long)(c0 + ty + i) * R + r0 + tx] = f2bf(t[tx][ty + i]);
}

// ============ 256^2 8-phase NT GEMM — read-hoisted schedule ============
// Each phase: {stage; lgkmcnt(0) [waits reads issued LAST phase]; [ph4/ph8: vmcnt+mid-barrier];
//              16 MFMA; issue NEXT phase's frag reads; s_barrier}
// LDS reads drain during other waves' MFMA + barrier wait. Stages placed so every stage
// is >=1 barrier after the target region's reads were lgkm-waited.
// Steady-state VMEM in flight: vmcnt(4) at ph4/ph8 (final iter: vmcnt(0)).

__device__ __forceinline__ void stage_half(ushort* d, const ushort* s, int K) {
  gld16(d, s);
  gld16(d + 4096, s + (long)64 * K);
}

template <int M0>
__device__ __forceinline__ void rd_a(const ushort* __restrict__ T, int aO0, int aO1,
                                     bf16x8 (&af)[2][2]) {
  af[0][0] = *(const bf16x8*)&T[aO0 + M0 * 1024];
  af[0][1] = *(const bf16x8*)&T[aO1 + M0 * 1024];
  af[1][0] = *(const bf16x8*)&T[aO0 + (M0 + 1) * 1024];
  af[1][1] = *(const bf16x8*)&T[aO1 + (M0 + 1) * 1024];
}

__device__ __forceinline__ void rd_b8(const ushort* __restrict__ T, int bO0, int bO1,
                                      bf16x8 (&bf)[4][2]) {
  #pragma unroll
  for (int j = 0; j < 4; j++) {
    bf[j][0] = *(const bf16x8*)&T[bO0 + j * 1024];
    bf[j][1] = *(const bf16x8*)&T[bO1 + j * 1024];
  }
}

template <int M0>
__device__ __forceinline__ void mfma16(const bf16x8 (&af)[2][2], const bf16x8 (&bf)[4][2],
                                       f32x4 (&acc)[8][4]) {
  #pragma unroll
  for (int kk = 0; kk < 2; kk++)
    #pragma unroll
    for (int mm = 0; mm < 2; mm++)
      #pragma unroll
      for (int j = 0; j < 4; j++)
        acc[M0 + mm][j] = __builtin_amdgcn_mfma_f32_16x16x32_bf16(
            af[mm][kk], bf[j][kk], acc[M0 + mm][j], 0, 0, 0);
}

#define W_LGKM0 asm volatile("s_waitcnt lgkmcnt(0)" ::: "memory")
#define W_VM4   asm volatile("s_waitcnt vmcnt(4)" ::: "memory")
#define W_VM0   asm volatile("s_waitcnt vmcnt(0)" ::: "memory")
#define SBAR    asm volatile("s_barrier" ::: "memory")
#define SCHB    __builtin_amdgcn_sched_barrier(0)
#define PRIO1   __builtin_amdgcn_s_setprio(1)
#define PRIO0   __builtin_amdgcn_s_setprio(0)

// MODE 1: bf16 store | MODE 2: softplus(acc + csum*w0 + bexp) bf16 at col+colOff
// MODE 3: fp32 store | MODE 4: relu -> bf16 store + row-sum atomics into csum
template <int MODE>
__global__ __launch_bounds__(512, 2) void gemm8(
    const ushort* __restrict__ Ag, const ushort* __restrict__ Bg, void* __restrict__ Cg,
    int K, long sA, long sB, long sC, int ldc, int colOff,
    float* __restrict__ csum, const float* __restrict__ w0,
    const float* __restrict__ bexp) {
  extern __shared__ ushort lds[];   // [A0 16K | A1 16K | B0 16K | B1 16K] ushorts

  // XCD swizzle: lin%8 = "XCD" (round-robin assumption); each owns (z, y-half)
  const int lin = blockIdx.x + (blockIdx.y << 3) + (blockIdx.z << 6);
  const int xcd = lin & 7, m_ = lin >> 3;
  const int bz = xcd >> 1;
  const int by = ((xcd & 1) << 2) + (m_ >> 3);
  const int bx = m_ & 7;

  const ushort* A  = Ag + (long)bz * sA + (long)(bx << 8) * K;
  const ushort* Bp = Bg + (long)bz * sB + (long)(by << 8) * K;

  const int tid = threadIdx.x;
  // staging: thread covers linear half-tile bytes tid*16; global col pre-swizzled so
  // linear LDS holds the XOR-swizzled layout
  const int sr = tid >> 3;                         // row within half
  const int sc = ((tid & 7) ^ (sr & 7)) << 3;      // ushort col, XOR-swizzled
  const ushort* aS = A + (long)sr * K + sc;
  const ushort* bS = Bp + (long)sr * K + sc;
  const int wOff = (tid >> 6) << 9;                // wave-uniform LDS offset (ushorts)
  ushort* const stA0 = lds + wOff;
  ushort* const stA1 = lds + 16384 + wOff;
  ushort* const stB0 = lds + 32768 + wOff;
  ushort* const stB1 = lds + 49152 + wOff;
  const ushort* const TA0 = lds;          const ushort* const TA1 = lds + 16384;
  const ushort* const TB0 = lds + 32768;  const ushort* const TB1 = lds + 49152;

  auto stg = [&](ushort* base, const ushort* src, int T, int H) {
    stage_half(base + (H << 13), src + (long)(H << 7) * K + ((long)T << 6), K);
  };

  // fragment read offsets (swizzled)
  const int L = tid & 63, wid = tid >> 6;
  const int wr = wid >> 2, wc = wid & 3;
  const int fr = L & 15, g = L >> 4;
  const int off0 = ((g ^ (fr & 7)) << 3);
  const int aO0 = ((wr << 7) + fr) * 64 + off0, aO1 = aO0 ^ 32;
  const int bO0 = ((wc << 6) + fr) * 64 + off0, bO1 = bO0 ^ 32;

  f32x4 acc[8][4] = {};
  bf16x8 af[2][2], bf[4][2];

  const int NT = K >> 6, NTI = NT >> 1;

  // prologue: tile0 -> buf0 (8 loads), B(tile1) -> buf1 (4), A1h0(tile1) (2) = 14 issues
  stg(stB0, bS, 0, 0); stg(stB0, bS, 0, 1); stg(stA0, aS, 0, 0); stg(stA0, aS, 0, 1);
  stg(stB1, bS, 1, 0); stg(stB1, bS, 1, 1);
  stg(stA1, aS, 1, 0);
  asm volatile("s_waitcnt vmcnt(6)" ::: "memory");   // tile0 fully landed
  SBAR;
  // pre-reads for ph1 (B buf0 + A m0-1)
  rd_b8(TB0, bO0, bO1, bf);
  rd_a<0>(TA0, aO0, aO1, af);

  for (int it = 0; it < NTI; ++it) {
    const int t1 = 2 * it + 1, t2 = 2 * it + 2, t3 = 2 * it + 3;
    const bool more = (it + 1 < NTI);

    // ---- ph1: MFMA m0-1 (buf0) ----
    stg(stA1, aS, t1, 1);                 // A1h1(T1)
    W_LGKM0; SCHB;
    PRIO1; mfma16<0>(af, bf, acc); PRIO0; SCHB;
    rd_a<2>(TA0, aO0, aO1, af);
    SBAR;
    // ---- ph2: MFMA m2-3 ----
    if (more) stg(stB0, bS, t2, 0);       // B0h0(T2)
    W_LGKM0; SCHB;
    PRIO1; mfma16<2>(af, bf, acc); PRIO0; SCHB;
    rd_a<4>(TA0, aO0, aO1, af);
    SBAR;
    // ---- ph3: MFMA m4-5 ----
    if (more) stg(stB0, bS, t2, 1);       // B0h1(T2)
    W_LGKM0; SCHB;
    PRIO1; mfma16<4>(af, bf, acc); PRIO0; SCHB;
    rd_a<6>(TA0, aO0, aO1, af);
    SBAR;
    // ---- ph4: MFMA m6-7; then switch to buf1 reads ----
    W_LGKM0;
    if (more) { W_VM4; } else { W_VM0; }  // force tile T1 (buf1) landed
    SBAR;                                 // all waves' T1 slices visible
    SCHB;
    PRIO1; mfma16<6>(af, bf, acc); PRIO0; SCHB;
    rd_b8(TB1, bO0, bO1, bf);
    rd_a<0>(TA1, aO0, aO1, af);
    SBAR;
    // ---- ph5: MFMA m0-1 (buf1) ----
    if (more) stg(stA0, aS, t2, 0);       // A0h0(T2)
    W_LGKM0; SCHB;
    PRIO1; mfma16<0>(af, bf, acc); PRIO0; SCHB;
    rd_a<2>(TA1, aO0, aO1, af);
    SBAR;
    // ---- ph6: MFMA m2-3 ----
    if (more) stg(stA0, aS, t2, 1);       // A0h1(T2)
    W_LGKM0; SCHB;
    PRIO1; mfma16<2>(af, bf, acc); PRIO0; SCHB;
    rd_a<4>(TA1, aO0, aO1, af);
    SBAR;
    // ---- ph7: MFMA m4-5 ----
    if (more) stg(stB1, bS, t3, 0);       // B1h0(T3)
    W_LGKM0; SCHB;
    PRIO1; mfma16<4>(af, bf, acc); PRIO0; SCHB;
    rd_a<6>(TA1, aO0, aO1, af);
    SBAR;
    // ---- ph8: MFMA m6-7; then switch to buf0 (tile T2) reads ----
    if (more) stg(stB1, bS, t3, 1);       // B1h1(T3)
    W_LGKM0;
    if (more) { W_VM4; }                  // force tile T2 (buf0) landed
    SBAR;
    SCHB;
    PRIO1; mfma16<6>(af, bf, acc); PRIO0; SCHB;
    if (more) {
      rd_b8(TB0, bO0, bO1, bf);
      rd_a<0>(TA0, aO0, aO1, af);
      stg(stA1, aS, t3, 0);               // A1h0(T3) — extra lead for next iter's ph4
    }
    SBAR;
  }

  // ---------------- vectorized epilogue (per-wave private LDS patch) ----------------
  const int cq = fr;                      // fragment col within 16x16 quad
  const int rowB0 = (bx << 8) + (wr << 7);
  const int colB0 = (by << 8) + (wc << 6);

  if (MODE == 3) {
    // per-wave 16x64 fp32 patch, pitch 68 floats (272B rows, 16B-aligned)
    float* eT = (float*)lds + (size_t)wid * 1088;
    float* Cb = (float*)Cg + (long)bz * sC;
    const int er = L >> 4, ec = L & 15;
    #pragma unroll
    for (int m = 0; m < 8; m++) {
      #pragma unroll
      for (int j = 0; j < 4; j++)
        #pragma unroll
        for (int r = 0; r < 4; r++)
          eT[(g * 4 + r) * 68 + j * 16 + cq] = acc[m][j][r];
      #pragma unroll
      for (int q = 0; q < 4; q++) {
        const f32x4 v = *(const f32x4*)&eT[(er + q * 4) * 68 + ec * 4];
        const long row = rowB0 + m * 16 + er + q * 4;
        *(f32x4*)&Cb[row * ldc + colB0 + ec * 4] = v;   // 16 lanes x 16B = 256B/row
      }
    }
  } else {
    // per-wave 16x64 bf16 patch, pitch 72 ushorts (144B rows, 16B-aligned)
    ushort* eT = lds + (size_t)wid * 1152;
    ushort* Cb = (ushort*)Cg + (long)bz * sC;
    const int er = L >> 3, ec = L & 7;
    float w0v[4], bev[4];
    if (MODE == 2) {
      #pragma unroll
      for (int j = 0; j < 4; j++) {
        w0v[j] = w0[colB0 + j * 16 + cq];
        bev[j] = bexp[colB0 + j * 16 + cq];
      }
    }
    #pragma unroll
    for (int m = 0; m < 8; m++) {
      float rsr[4] = {0.f, 0.f, 0.f, 0.f};
      #pragma unroll
      for (int j = 0; j < 4; j++)
        #pragma unroll
        for (int r = 0; r < 4; r++) {
          float x = acc[m][j][r];
          if (MODE == 2) {
            const float cv = csum[(long)bz * N_ + rowB0 + m * 16 + g * 4 + r];
            x = x + cv * w0v[j] + bev[j];
            x = fmaxf(x, 0.f) + log1pf(expf(-fabsf(x)));
          }
          if (MODE == 4) {
            x = fmaxf(x, 0.f);
            rsr[r] += x;
          }
          eT[(g * 4 + r) * 72 + j * 16 + cq] = f2bf(x);
        }
      if (MODE == 4) {
        // reduce across 16 fr-lanes (same g) -> wave's 64-col partial row sum
        #pragma unroll
        for (int r = 0; r < 4; r++) {
          float s = rsr[r];
          s += __shfl_xor(s, 1); s += __shfl_xor(s, 2);
          s += __shfl_xor(s, 4); s += __shfl_xor(s, 8);
          if (fr == 0)
            atomicAdd(&csum[(long)bz * N_ + rowB0 + m * 16 + g * 4 + r], s);
        }
      }
      #pragma unroll
      for (int q = 0; q < 2; q++) {
        const uint4 v = *(const uint4*)&eT[(er + q * 8) * 72 + ec * 8];
        const long row = rowB0 + m * 16 + er + q * 8;
        *(uint4*)&Cb[row * ldc + colOff + colB0 + ec * 8] = v;  // 8 lanes x 16B = 128B/row
      }
    }
  }
}

// ---------------- launch ----------------
extern "C" void kernel_launch(void* const* d_in, const int* in_sizes, int n_in,
                              void* d_out, int out_size, void* d_ws, size_t ws_size,
                              hipStream_t stream) {
  const float* data    = (const float*)d_in[0];
  const float* W_exp   = (const float*)d_in[1];
  const float* b_exp   = (const float*)d_in[2];
  const float* W_merge = (const float*)d_in[3];

  char* ws = (char*)d_ws;
  const size_t MB = 1024 * 1024;
  ushort* cnv  = (ushort*)(ws);             // 32MB: cn, then reused as v_out
  ushort* sim  = (ushort*)(ws + 32 * MB);   // 32MB
  ushort* pe   = (ushort*)(ws + 64 * MB);   // 8MB
  ushort* weT  = (ushort*)(ws + 72 * MB);   // 8MB:  W_exp[1:,:]^T
  ushort* wmT  = (ushort*)(ws + 80 * MB);   // 16MB: W_merge^T
  ushort* catA = (ushort*)(ws + 96 * MB);   // 64MB: [data | counter] bf16
  float*  csum = (float*)(ws + 160 * MB);   // 128KB

  static bool attrs_set = false;
  if (!attrs_set) {
    (void)hipFuncSetAttribute((const void*)gemm8<1>, hipFuncAttributeMaxDynamicSharedMemorySize, 131072);
    (void)hipFuncSetAttribute((const void*)gemm8<2>, hipFuncAttributeMaxDynamicSharedMemorySize, 131072);
    (void)hipFuncSetAttribute((const void*)gemm8<3>, hipFuncAttributeMaxDynamicSharedMemorySize, 131072);
    (void)hipFuncSetAttribute((const void*)gemm8<4>, hipFuncAttributeMaxDynamicSharedMemorySize, 131072);
    attrs_set = true;
  }

  hipMemsetAsync(csum, 0, (size_t)B_ * N_ * sizeof(float), stream);
  prep_cn<<<B_ * N_, 256, 0, stream>>>(data, cnv, catA);
  prep_pe<<<(N_ * N_) / 256, 256, 0, stream>>>(pe);
  transpose_bf16<<<dim3(D_ / 32, D_ / 32), dim3(32, 8), 0, stream>>>(W_exp + D_, weT, D_, D_);
  transpose_bf16<<<dim3(D_ / 32, (2 * D_) / 32), dim3(32, 8), 0, stream>>>(W_merge, wmT, 2 * D_, D_);

  dim3 g8(N_ / 256, N_ / 256, B_);
  // G1: sim = relu(cn cn^T) full grid (NT: B operand = cn rows), row-sums -> csum
  gemm8<4><<<g8, 512, 131072, stream>>>(cnv, cnv, sim, N_, (long)N_ * D_, (long)N_ * D_,
                                        (long)N_ * N_, N_, 0, csum, nullptr, nullptr);
  // G2: v_out = pe @ sim  (sim symmetric -> NT form), into cnv region (cn is dead)
  gemm8<1><<<g8, 512, 131072, stream>>>(pe, sim, cnv, N_, 0, (long)N_ * N_,
                                        (long)N_ * N_, N_, 0, nullptr, nullptr, nullptr);
  // G3: catA[:, D:] = softplus(v_out @ W_exp[1:] + csum*w0 + b_exp)
  gemm8<2><<<g8, 512, 131072, stream>>>(cnv, weT, catA, N_, (long)N_ * N_, 0,
                                        (long)N_ * 2 * D_, 2 * D_, D_, csum, W_exp, b_exp);
  // G4: out = catA @ W_merge
  gemm8<3><<<g8, 512, 131072, stream>>>(catA, wmT, d_out, 2 * D_, (long)N_ * 2 * D_, 0,
                                        (long)N_ * D_, D_, 0, nullptr, nullptr, nullptr);
}

// Round 6
// 488.356 us; speedup vs baseline: 1.1506x; 1.0049x over previous
//
#include <hip/hip_runtime.h>

#define B_ 4
#define N_ 2048
#define D_ 2048

typedef __bf16 bf16x8 __attribute__((ext_vector_type(8)));
typedef float  f32x4  __attribute__((ext_vector_type(4)));

__device__ __forceinline__ ushort f2bf(float x) {
  union { float f; unsigned u; } c; c.f = x;
  unsigned u = c.u;
  u += 0x7fffu + ((u >> 16) & 1u);   // RNE
  return (ushort)(u >> 16);
}

// async global->LDS, 16B per lane; lds base must be wave-uniform (HW adds lane*16)
__device__ __forceinline__ void gld16(ushort* lds, const ushort* g) {
  __builtin_amdgcn_global_load_lds(
      (const __attribute__((address_space(1))) void*)g,
      (__attribute__((address_space(3))) void*)lds, 16, 0, 0);
}

// ---------------- fused prep kernel ----------------
// roles by blockIdx.x:
//   [0,8192)      : cn = l2norm(data) bf16; catA[:, :D] = bf16(data)
//   [8192,16384)  : posenc pairs (sin,cos share angle) -> pe
//   [16384,20480) : weT = bf16(W_exp[1:,:]^T)   (D x D)
//   [20480,28672) : wmT = bf16(W_merge^T)       (D x 2D out)
#define PREP_BLOCKS 28672

__device__ __forceinline__ void do_transpose(const float* __restrict__ in,
                                             ushort* __restrict__ out,
                                             int R, int C, int bx, int byy, int tid) {
  __shared__ float t[32][33];
  const int c0 = bx * 32, r0 = byy * 32;
  const int tx = tid & 31, ty = tid >> 5;   // (32,8)
  #pragma unroll
  for (int i = 0; i < 32; i += 8) t[ty + i][tx] = in[(long)(r0 + ty + i) * C + c0 + tx];
  __syncthreads();
  #pragma unroll
  for (int i = 0; i < 32; i += 8) out[(long)(c0 + ty + i) * R + r0 + tx] = f2bf(t[tx][ty + i]);
}

__global__ __launch_bounds__(256) void prep_all(
    const float* __restrict__ data, ushort* __restrict__ cn, ushort* __restrict__ catA,
    ushort* __restrict__ pe, const float* __restrict__ W_exp, ushort* __restrict__ weT,
    const float* __restrict__ W_merge, ushort* __restrict__ wmT) {
  const int b = blockIdx.x;
  const int tid = threadIdx.x;

  if (b < 8192) {
    // ---- cn / catA role ----
    const int row = b;                         // 0..B*N-1
    const long base = (long)row * D_;
    const float4* r4 = (const float4*)(data + base);
    float4 u0 = r4[tid * 2], u1 = r4[tid * 2 + 1];
    float s = u0.x*u0.x + u0.y*u0.y + u0.z*u0.z + u0.w*u0.w
            + u1.x*u1.x + u1.y*u1.y + u1.z*u1.z + u1.w*u1.w;
    #pragma unroll
    for (int o = 32; o > 0; o >>= 1) s += __shfl_down(s, o);
    __shared__ float wsum[4];
    if ((tid & 63) == 0) wsum[tid >> 6] = s;
    __syncthreads();
    const float tot = wsum[0] + wsum[1] + wsum[2] + wsum[3];
    const float sc = rsqrtf(fmaxf(tot, 1e-12f));
    uint4 pc, pd;
    pc.x = (unsigned)f2bf(u0.x * sc) | ((unsigned)f2bf(u0.y * sc) << 16);
    pc.y = (unsigned)f2bf(u0.z * sc) | ((unsigned)f2bf(u0.w * sc) << 16);
    pc.z = (unsigned)f2bf(u1.x * sc) | ((unsigned)f2bf(u1.y * sc) << 16);
    pc.w = (unsigned)f2bf(u1.z * sc) | ((unsigned)f2bf(u1.w * sc) << 16);
    pd.x = (unsigned)f2bf(u0.x) | ((unsigned)f2bf(u0.y) << 16);
    pd.y = (unsigned)f2bf(u0.z) | ((unsigned)f2bf(u0.w) << 16);
    pd.z = (unsigned)f2bf(u1.x) | ((unsigned)f2bf(u1.y) << 16);
    pd.w = (unsigned)f2bf(u1.z) | ((unsigned)f2bf(u1.w) << 16);
    *(uint4*)(cn + base + tid * 8) = pc;
    *(uint4*)(catA + (long)row * (2 * D_) + tid * 8) = pd;
  } else if (b < 16384) {
    // ---- posenc role: one thread per (sin,cos) pair ----
    const int id = (b - 8192) * 256 + tid;     // 0..N*D/2-1
    const int n = id >> 10;                    // D/2 = 1024 pairs per row
    const int dp = id & 1023;
    const float e = (float)dp * (1.0f / 1024.0f);
    const float rate = __expf(e * -9.210340371976184f);   // 10000^-e
    const float ang = (float)n * rate;
    // reduce to [0,1) revolutions in fp32 (err <= ~2e-5 rev, << bf16 ulp), fast-path trig
    float rev = ang * 0.15915494309189535f;
    rev -= floorf(rev);
    const float ar = rev * 6.283185307179586f;
    const float sv = __sinf(ar);
    const float cv = __cosf(ar);
    *(unsigned*)(pe + (long)n * D_ + 2 * dp) =
        (unsigned)f2bf(sv) | ((unsigned)f2bf(cv) << 16);
  } else if (b < 20480) {
    // ---- W_exp[1:,:] transpose role ----
    const int blk = b - 16384;                 // 4096 blocks: 64x64 tiles
    do_transpose(W_exp + D_, weT, D_, D_, blk & 63, blk >> 6, tid);
  } else {
    // ---- W_merge transpose role ----
    const int blk = b - 20480;                 // 8192 blocks: 64x128 tiles
    do_transpose(W_merge, wmT, 2 * D_, D_, blk & 63, blk >> 6, tid);
  }
}

// ============ 256^2 8-phase NT GEMM — read-hoisted schedule ============
// Each phase: {stage; lgkmcnt(0) [waits reads issued LAST phase]; [ph4/ph8: vmcnt+mid-barrier];
//              16 MFMA; issue NEXT phase's frag reads; s_barrier}
// LDS reads drain during other waves' MFMA + barrier wait. Stages placed so every stage
// is >=1 barrier after the target region's reads were lgkm-waited.
// Steady-state VMEM in flight: vmcnt(4) at ph4/ph8 (final iter: vmcnt(0)).

__device__ __forceinline__ void stage_half(ushort* d, const ushort* s, int K) {
  gld16(d, s);
  gld16(d + 4096, s + (long)64 * K);
}

template <int M0>
__device__ __forceinline__ void rd_a(const ushort* __restrict__ T, int aO0, int aO1,
                                     bf16x8 (&af)[2][2]) {
  af[0][0] = *(const bf16x8*)&T[aO0 + M0 * 1024];
  af[0][1] = *(const bf16x8*)&T[aO1 + M0 * 1024];
  af[1][0] = *(const bf16x8*)&T[aO0 + (M0 + 1) * 1024];
  af[1][1] = *(const bf16x8*)&T[aO1 + (M0 + 1) * 1024];
}

__device__ __forceinline__ void rd_b8(const ushort* __restrict__ T, int bO0, int bO1,
                                      bf16x8 (&bf)[4][2]) {
  #pragma unroll
  for (int j = 0; j < 4; j++) {
    bf[j][0] = *(const bf16x8*)&T[bO0 + j * 1024];
    bf[j][1] = *(const bf16x8*)&T[bO1 + j * 1024];
  }
}

template <int M0>
__device__ __forceinline__ void mfma16(const bf16x8 (&af)[2][2], const bf16x8 (&bf)[4][2],
                                       f32x4 (&acc)[8][4]) {
  #pragma unroll
  for (int kk = 0; kk < 2; kk++)
    #pragma unroll
    for (int mm = 0; mm < 2; mm++)
      #pragma unroll
      for (int j = 0; j < 4; j++)
        acc[M0 + mm][j] = __builtin_amdgcn_mfma_f32_16x16x32_bf16(
            af[mm][kk], bf[j][kk], acc[M0 + mm][j], 0, 0, 0);
}

#define W_LGKM0 asm volatile("s_waitcnt lgkmcnt(0)" ::: "memory")
#define W_VM4   asm volatile("s_waitcnt vmcnt(4)" ::: "memory")
#define W_VM0   asm volatile("s_waitcnt vmcnt(0)" ::: "memory")
#define SBAR    asm volatile("s_barrier" ::: "memory")
#define SCHB    __builtin_amdgcn_sched_barrier(0)
#define PRIO1   __builtin_amdgcn_s_setprio(1)
#define PRIO0   __builtin_amdgcn_s_setprio(0)

// MODE 1: bf16 store | MODE 2: softplus(acc + csum*w0 + bexp) bf16 at col+colOff
// MODE 3: fp32 store | MODE 4: relu -> bf16 store + row-sum atomics into csum
template <int MODE>
__global__ __launch_bounds__(512, 2) void gemm8(
    const ushort* __restrict__ Ag, const ushort* __restrict__ Bg, void* __restrict__ Cg,
    int K, long sA, long sB, long sC, int ldc, int colOff,
    float* __restrict__ csum, const float* __restrict__ w0,
    const float* __restrict__ bexp) {
  extern __shared__ ushort lds[];   // [A0 16K | A1 16K | B0 16K | B1 16K] ushorts

  // XCD swizzle: lin%8 = "XCD" (round-robin assumption); each owns (z, y-half)
  const int lin = blockIdx.x + (blockIdx.y << 3) + (blockIdx.z << 6);
  const int xcd = lin & 7, m_ = lin >> 3;
  const int bz = xcd >> 1;
  const int by = ((xcd & 1) << 2) + (m_ >> 3);
  const int bx = m_ & 7;

  const ushort* A  = Ag + (long)bz * sA + (long)(bx << 8) * K;
  const ushort* Bp = Bg + (long)bz * sB + (long)(by << 8) * K;

  const int tid = threadIdx.x;
  // staging: thread covers linear half-tile bytes tid*16; global col pre-swizzled so
  // linear LDS holds the XOR-swizzled layout
  const int sr = tid >> 3;                         // row within half
  const int sc = ((tid & 7) ^ (sr & 7)) << 3;      // ushort col, XOR-swizzled
  const ushort* aS = A + (long)sr * K + sc;
  const ushort* bS = Bp + (long)sr * K + sc;
  const int wOff = (tid >> 6) << 9;                // wave-uniform LDS offset (ushorts)
  ushort* const stA0 = lds + wOff;
  ushort* const stA1 = lds + 16384 + wOff;
  ushort* const stB0 = lds + 32768 + wOff;
  ushort* const stB1 = lds + 49152 + wOff;
  const ushort* const TA0 = lds;          const ushort* const TA1 = lds + 16384;
  const ushort* const TB0 = lds + 32768;  const ushort* const TB1 = lds + 49152;

  auto stg = [&](ushort* base, const ushort* src, int T, int H) {
    stage_half(base + (H << 13), src + (long)(H << 7) * K + ((long)T << 6), K);
  };

  // fragment read offsets (swizzled)
  const int L = tid & 63, wid = tid >> 6;
  const int wr = wid >> 2, wc = wid & 3;
  const int fr = L & 15, g = L >> 4;
  const int off0 = ((g ^ (fr & 7)) << 3);
  const int aO0 = ((wr << 7) + fr) * 64 + off0, aO1 = aO0 ^ 32;
  const int bO0 = ((wc << 6) + fr) * 64 + off0, bO1 = bO0 ^ 32;

  f32x4 acc[8][4] = {};
  bf16x8 af[2][2], bf[4][2];

  const int NT = K >> 6, NTI = NT >> 1;

  // prologue: tile0 -> buf0 (8 loads), B(tile1) -> buf1 (4), A1h0(tile1) (2) = 14 issues
  stg(stB0, bS, 0, 0); stg(stB0, bS, 0, 1); stg(stA0, aS, 0, 0); stg(stA0, aS, 0, 1);
  stg(stB1, bS, 1, 0); stg(stB1, bS, 1, 1);
  stg(stA1, aS, 1, 0);
  asm volatile("s_waitcnt vmcnt(6)" ::: "memory");   // tile0 fully landed
  SBAR;
  // pre-reads for ph1 (B buf0 + A m0-1)
  rd_b8(TB0, bO0, bO1, bf);
  rd_a<0>(TA0, aO0, aO1, af);

  for (int it = 0; it < NTI; ++it) {
    const int t1 = 2 * it + 1, t2 = 2 * it + 2, t3 = 2 * it + 3;
    const bool more = (it + 1 < NTI);

    // ---- ph1: MFMA m0-1 (buf0) ----
    stg(stA1, aS, t1, 1);                 // A1h1(T1)
    W_LGKM0; SCHB;
    PRIO1; mfma16<0>(af, bf, acc); PRIO0; SCHB;
    rd_a<2>(TA0, aO0, aO1, af);
    SBAR;
    // ---- ph2: MFMA m2-3 ----
    if (more) stg(stB0, bS, t2, 0);       // B0h0(T2)
    W_LGKM0; SCHB;
    PRIO1; mfma16<2>(af, bf, acc); PRIO0; SCHB;
    rd_a<4>(TA0, aO0, aO1, af);
    SBAR;
    // ---- ph3: MFMA m4-5 ----
    if (more) stg(stB0, bS, t2, 1);       // B0h1(T2)
    W_LGKM0; SCHB;
    PRIO1; mfma16<4>(af, bf, acc); PRIO0; SCHB;
    rd_a<6>(TA0, aO0, aO1, af);
    SBAR;
    // ---- ph4: MFMA m6-7; then switch to buf1 reads ----
    W_LGKM0;
    if (more) { W_VM4; } else { W_VM0; }  // force tile T1 (buf1) landed
    SBAR;                                 // all waves' T1 slices visible
    SCHB;
    PRIO1; mfma16<6>(af, bf, acc); PRIO0; SCHB;
    rd_b8(TB1, bO0, bO1, bf);
    rd_a<0>(TA1, aO0, aO1, af);
    SBAR;
    // ---- ph5: MFMA m0-1 (buf1) ----
    if (more) stg(stA0, aS, t2, 0);       // A0h0(T2)
    W_LGKM0; SCHB;
    PRIO1; mfma16<0>(af, bf, acc); PRIO0; SCHB;
    rd_a<2>(TA1, aO0, aO1, af);
    SBAR;
    // ---- ph6: MFMA m2-3 ----
    if (more) stg(stA0, aS, t2, 1);       // A0h1(T2)
    W_LGKM0; SCHB;
    PRIO1; mfma16<2>(af, bf, acc); PRIO0; SCHB;
    rd_a<4>(TA1, aO0, aO1, af);
    SBAR;
    // ---- ph7: MFMA m4-5 ----
    if (more) stg(stB1, bS, t3, 0);       // B1h0(T3)
    W_LGKM0; SCHB;
    PRIO1; mfma16<4>(af, bf, acc); PRIO0; SCHB;
    rd_a<6>(TA1, aO0, aO1, af);
    SBAR;
    // ---- ph8: MFMA m6-7; then switch to buf0 (tile T2) reads ----
    if (more) stg(stB1, bS, t3, 1);       // B1h1(T3)
    W_LGKM0;
    if (more) { W_VM4; }                  // force tile T2 (buf0) landed
    SBAR;
    SCHB;
    PRIO1; mfma16<6>(af, bf, acc); PRIO0; SCHB;
    if (more) {
      rd_b8(TB0, bO0, bO1, bf);
      rd_a<0>(TA0, aO0, aO1, af);
      stg(stA1, aS, t3, 0);               // A1h0(T3) — extra lead for next iter's ph4
    }
    SBAR;
  }

  // ---------------- vectorized epilogue (per-wave private LDS patch) ----------------
  const int cq = fr;                      // fragment col within 16x16 quad
  const int rowB0 = (bx << 8) + (wr << 7);
  const int colB0 = (by << 8) + (wc << 6);

  if (MODE == 3) {
    // per-wave 16x64 fp32 patch, pitch 68 floats (272B rows, 16B-aligned)
    float* eT = (float*)lds + (size_t)wid * 1088;
    float* Cb = (float*)Cg + (long)bz * sC;
    const int er = L >> 4, ec = L & 15;
    #pragma unroll
    for (int m = 0; m < 8; m++) {
      #pragma unroll
      for (int j = 0; j < 4; j++)
        #pragma unroll
        for (int r = 0; r < 4; r++)
          eT[(g * 4 + r) * 68 + j * 16 + cq] = acc[m][j][r];
      #pragma unroll
      for (int q = 0; q < 4; q++) {
        const f32x4 v = *(const f32x4*)&eT[(er + q * 4) * 68 + ec * 4];
        const long row = rowB0 + m * 16 + er + q * 4;
        *(f32x4*)&Cb[row * ldc + colB0 + ec * 4] = v;   // 16 lanes x 16B = 256B/row
      }
    }
  } else {
    // per-wave 16x64 bf16 patch, pitch 72 ushorts (144B rows, 16B-aligned)
    ushort* eT = lds + (size_t)wid * 1152;
    ushort* Cb = (ushort*)Cg + (long)bz * sC;
    const int er = L >> 3, ec = L & 7;
    float w0v[4], bev[4];
    if (MODE == 2) {
      #pragma unroll
      for (int j = 0; j < 4; j++) {
        w0v[j] = w0[colB0 + j * 16 + cq];
        bev[j] = bexp[colB0 + j * 16 + cq];
      }
    }
    #pragma unroll
    for (int m = 0; m < 8; m++) {
      float rsr[4] = {0.f, 0.f, 0.f, 0.f};
      #pragma unroll
      for (int j = 0; j < 4; j++)
        #pragma unroll
        for (int r = 0; r < 4; r++) {
          float x = acc[m][j][r];
          if (MODE == 2) {
            const float cv = csum[(long)bz * N_ + rowB0 + m * 16 + g * 4 + r];
            x = x + cv * w0v[j] + bev[j];
            x = fmaxf(x, 0.f) + log1pf(expf(-fabsf(x)));
          }
          if (MODE == 4) {
            x = fmaxf(x, 0.f);
            rsr[r] += x;
          }
          eT[(g * 4 + r) * 72 + j * 16 + cq] = f2bf(x);
        }
      if (MODE == 4) {
        // reduce across 16 fr-lanes (same g) -> wave's 64-col partial row sum
        #pragma unroll
        for (int r = 0; r < 4; r++) {
          float s = rsr[r];
          s += __shfl_xor(s, 1); s += __shfl_xor(s, 2);
          s += __shfl_xor(s, 4); s += __shfl_xor(s, 8);
          if (fr == 0)
            atomicAdd(&csum[(long)bz * N_ + rowB0 + m * 16 + g * 4 + r], s);
        }
      }
      #pragma unroll
      for (int q = 0; q < 2; q++) {
        const uint4 v = *(const uint4*)&eT[(er + q * 8) * 72 + ec * 8];
        const long row = rowB0 + m * 16 + er + q * 8;
        *(uint4*)&Cb[row * ldc + colOff + colB0 + ec * 8] = v;  // 8 lanes x 16B = 128B/row
      }
    }
  }
}

// ---------------- launch ----------------
extern "C" void kernel_launch(void* const* d_in, const int* in_sizes, int n_in,
                              void* d_out, int out_size, void* d_ws, size_t ws_size,
                              hipStream_t stream) {
  const float* data    = (const float*)d_in[0];
  const float* W_exp   = (const float*)d_in[1];
  const float* b_exp   = (const float*)d_in[2];
  const float* W_merge = (const float*)d_in[3];

  char* ws = (char*)d_ws;
  const size_t MB = 1024 * 1024;
  ushort* cnv  = (ushort*)(ws);             // 32MB: cn, then reused as v_out
  ushort* sim  = (ushort*)(ws + 32 * MB);   // 32MB
  ushort* pe   = (ushort*)(ws + 64 * MB);   // 8MB
  ushort* weT  = (ushort*)(ws + 72 * MB);   // 8MB:  W_exp[1:,:]^T
  ushort* wmT  = (ushort*)(ws + 80 * MB);   // 16MB: W_merge^T
  ushort* catA = (ushort*)(ws + 96 * MB);   // 64MB: [data | counter] bf16
  float*  csum = (float*)(ws + 160 * MB);   // 128KB

  static bool attrs_set = false;
  if (!attrs_set) {
    (void)hipFuncSetAttribute((const void*)gemm8<1>, hipFuncAttributeMaxDynamicSharedMemorySize, 131072);
    (void)hipFuncSetAttribute((const void*)gemm8<2>, hipFuncAttributeMaxDynamicSharedMemorySize, 131072);
    (void)hipFuncSetAttribute((const void*)gemm8<3>, hipFuncAttributeMaxDynamicSharedMemorySize, 131072);
    (void)hipFuncSetAttribute((const void*)gemm8<4>, hipFuncAttributeMaxDynamicSharedMemorySize, 131072);
    attrs_set = true;
  }

  hipMemsetAsync(csum, 0, (size_t)B_ * N_ * sizeof(float), stream);
  prep_all<<<PREP_BLOCKS, 256, 0, stream>>>(data, cnv, catA, pe, W_exp, weT, W_merge, wmT);

  dim3 g8(N_ / 256, N_ / 256, B_);
  // G1: sim = relu(cn cn^T) full grid (NT: B operand = cn rows), row-sums -> csum
  gemm8<4><<<g8, 512, 131072, stream>>>(cnv, cnv, sim, N_, (long)N_ * D_, (long)N_ * D_,
                                        (long)N_ * N_, N_, 0, csum, nullptr, nullptr);
  // G2: v_out = pe @ sim  (sim symmetric -> NT form), into cnv region (cn is dead)
  gemm8<1><<<g8, 512, 131072, stream>>>(pe, sim, cnv, N_, 0, (long)N_ * N_,
                                        (long)N_ * N_, N_, 0, nullptr, nullptr, nullptr);
  // G3: catA[:, D:] = softplus(v_out @ W_exp[1:] + csum*w0 + b_exp)
  gemm8<2><<<g8, 512, 131072, stream>>>(cnv, weT, catA, N_, (long)N_ * N_, 0,
                                        (long)N_ * 2 * D_, 2 * D_, D_, csum, W_exp, b_exp);
  // G4: out = catA @ W_merge
  gemm8<3><<<g8, 512, 131072, stream>>>(catA, wmT, d_out, 2 * D_, (long)N_ * 2 * D_, 0,
                                        (long)N_ * D_, D_, 0, nullptr, nullptr, nullptr);
}

// Round 7
// 474.920 us; speedup vs baseline: 1.1832x; 1.0283x over previous
//
#include <hip/hip_runtime.h>

#define B_ 4
#define N_ 2048
#define D_ 2048

typedef __bf16 bf16x8 __attribute__((ext_vector_type(8)));
typedef float  f32x4  __attribute__((ext_vector_type(4)));

__device__ __forceinline__ ushort f2bf(float x) {
  union { float f; unsigned u; } c; c.f = x;
  unsigned u = c.u;
  u += 0x7fffu + ((u >> 16) & 1u);   // RNE
  return (ushort)(u >> 16);
}

// async global->LDS, 16B per lane; lds base must be wave-uniform (HW adds lane*16)
__device__ __forceinline__ void gld16(ushort* lds, const ushort* g) {
  __builtin_amdgcn_global_load_lds(
      (const __attribute__((address_space(1))) void*)g,
      (__attribute__((address_space(3))) void*)lds, 16, 0, 0);
}

// ---------------- fused prep kernel ----------------
// roles by blockIdx.x:
//   [0,8192)      : cn = l2norm(data) bf16; catA[:, :D] = bf16(data)
//   [8192,16384)  : posenc pairs (sin,cos share angle) -> pe
//   [16384,20480) : weT = bf16(W_exp[1:,:]^T)   (D x D)
//   [20480,28672) : wmT = bf16(W_merge^T)       (D x 2D out)
#define PREP_BLOCKS 28672

__device__ __forceinline__ void do_transpose(const float* __restrict__ in,
                                             ushort* __restrict__ out,
                                             int R, int C, int bx, int byy, int tid) {
  __shared__ float t[32][33];
  const int c0 = bx * 32, r0 = byy * 32;
  const int tx = tid & 31, ty = tid >> 5;   // (32,8)
  #pragma unroll
  for (int i = 0; i < 32; i += 8) t[ty + i][tx] = in[(long)(r0 + ty + i) * C + c0 + tx];
  __syncthreads();
  #pragma unroll
  for (int i = 0; i < 32; i += 8) out[(long)(c0 + ty + i) * R + r0 + tx] = f2bf(t[tx][ty + i]);
}

__global__ __launch_bounds__(256) void prep_all(
    const float* __restrict__ data, ushort* __restrict__ cn, ushort* __restrict__ catA,
    ushort* __restrict__ pe, const float* __restrict__ W_exp, ushort* __restrict__ weT,
    const float* __restrict__ W_merge, ushort* __restrict__ wmT) {
  const int b = blockIdx.x;
  const int tid = threadIdx.x;

  if (b < 8192) {
    // ---- cn / catA role ----
    const int row = b;                         // 0..B*N-1
    const long base = (long)row * D_;
    const float4* r4 = (const float4*)(data + base);
    float4 u0 = r4[tid * 2], u1 = r4[tid * 2 + 1];
    float s = u0.x*u0.x + u0.y*u0.y + u0.z*u0.z + u0.w*u0.w
            + u1.x*u1.x + u1.y*u1.y + u1.z*u1.z + u1.w*u1.w;
    #pragma unroll
    for (int o = 32; o > 0; o >>= 1) s += __shfl_down(s, o);
    __shared__ float wsum[4];
    if ((tid & 63) == 0) wsum[tid >> 6] = s;
    __syncthreads();
    const float tot = wsum[0] + wsum[1] + wsum[2] + wsum[3];
    const float sc = rsqrtf(fmaxf(tot, 1e-12f));
    uint4 pc, pd;
    pc.x = (unsigned)f2bf(u0.x * sc) | ((unsigned)f2bf(u0.y * sc) << 16);
    pc.y = (unsigned)f2bf(u0.z * sc) | ((unsigned)f2bf(u0.w * sc) << 16);
    pc.z = (unsigned)f2bf(u1.x * sc) | ((unsigned)f2bf(u1.y * sc) << 16);
    pc.w = (unsigned)f2bf(u1.z * sc) | ((unsigned)f2bf(u1.w * sc) << 16);
    pd.x = (unsigned)f2bf(u0.x) | ((unsigned)f2bf(u0.y) << 16);
    pd.y = (unsigned)f2bf(u0.z) | ((unsigned)f2bf(u0.w) << 16);
    pd.z = (unsigned)f2bf(u1.x) | ((unsigned)f2bf(u1.y) << 16);
    pd.w = (unsigned)f2bf(u1.z) | ((unsigned)f2bf(u1.w) << 16);
    *(uint4*)(cn + base + tid * 8) = pc;
    *(uint4*)(catA + (long)row * (2 * D_) + tid * 8) = pd;
  } else if (b < 16384) {
    // ---- posenc role: one thread per (sin,cos) pair ----
    const int id = (b - 8192) * 256 + tid;     // 0..N*D/2-1
    const int n = id >> 10;                    // D/2 = 1024 pairs per row
    const int dp = id & 1023;
    const float e = (float)dp * (1.0f / 1024.0f);
    const float rate = __expf(e * -9.210340371976184f);   // 10000^-e
    const float ang = (float)n * rate;
    // reduce to [0,1) revolutions in fp32 (err <= ~2e-5 rev, << bf16 ulp), fast-path trig
    float rev = ang * 0.15915494309189535f;
    rev -= floorf(rev);
    const float ar = rev * 6.283185307179586f;
    const float sv = __sinf(ar);
    const float cv = __cosf(ar);
    *(unsigned*)(pe + (long)n * D_ + 2 * dp) =
        (unsigned)f2bf(sv) | ((unsigned)f2bf(cv) << 16);
  } else if (b < 20480) {
    // ---- W_exp[1:,:] transpose role ----
    const int blk = b - 16384;                 // 4096 blocks: 64x64 tiles
    do_transpose(W_exp + D_, weT, D_, D_, blk & 63, blk >> 6, tid);
  } else {
    // ---- W_merge transpose role ----
    const int blk = b - 20480;                 // 8192 blocks: 64x128 tiles
    do_transpose(W_merge, wmT, 2 * D_, D_, blk & 63, blk >> 6, tid);
  }
}

// ============ 256^2 8-phase NT GEMM — read-hoisted, compiler-scheduled ============
// Phase = {stage (async); [ph4/ph8: counted vmcnt + mid-barrier]; setprio(1) 16 MFMA
// setprio(0); issue NEXT phase's frag reads; s_barrier}. No lgkm fences: fragment reads
// are ordinary vector loads, so the compiler inserts minimal counted lgkmcnt before the
// first consuming MFMA and interleaves reads into the MFMA stream as register lifetimes
// free (af[i] dead after its last MFMA). asm memory clobbers (s_barrier/vmcnt) pin
// reads and stages inside their phase. Stage placement: each stage >=1 barrier after
// the target region's reads complete. Steady-state vmcnt(4) at ph4/ph8.

__device__ __forceinline__ void stage_half(ushort* d, const ushort* s, int K) {
  gld16(d, s);
  gld16(d + 4096, s + (long)64 * K);
}

template <int M0>
__device__ __forceinline__ void rd_a(const ushort* __restrict__ T, int aO0, int aO1,
                                     bf16x8 (&af)[2][2]) {
  af[0][0] = *(const bf16x8*)&T[aO0 + M0 * 1024];
  af[0][1] = *(const bf16x8*)&T[aO1 + M0 * 1024];
  af[1][0] = *(const bf16x8*)&T[aO0 + (M0 + 1) * 1024];
  af[1][1] = *(const bf16x8*)&T[aO1 + (M0 + 1) * 1024];
}

__device__ __forceinline__ void rd_b8(const ushort* __restrict__ T, int bO0, int bO1,
                                      bf16x8 (&bf)[4][2]) {
  #pragma unroll
  for (int j = 0; j < 4; j++) {
    bf[j][0] = *(const bf16x8*)&T[bO0 + j * 1024];
    bf[j][1] = *(const bf16x8*)&T[bO1 + j * 1024];
  }
}

template <int M0>
__device__ __forceinline__ void mfma16(const bf16x8 (&af)[2][2], const bf16x8 (&bf)[4][2],
                                       f32x4 (&acc)[8][4]) {
  #pragma unroll
  for (int kk = 0; kk < 2; kk++)
    #pragma unroll
    for (int mm = 0; mm < 2; mm++)
      #pragma unroll
      for (int j = 0; j < 4; j++)
        acc[M0 + mm][j] = __builtin_amdgcn_mfma_f32_16x16x32_bf16(
            af[mm][kk], bf[j][kk], acc[M0 + mm][j], 0, 0, 0);
}

#define W_VM4   asm volatile("s_waitcnt vmcnt(4)" ::: "memory")
#define W_VM0   asm volatile("s_waitcnt vmcnt(0)" ::: "memory")
#define SBAR    asm volatile("s_barrier" ::: "memory")
#define PRIO1   __builtin_amdgcn_s_setprio(1)
#define PRIO0   __builtin_amdgcn_s_setprio(0)

// MODE 1: bf16 store | MODE 2: softplus(acc + csum*w0 + bexp) bf16 at col+colOff
// MODE 3: fp32 store | MODE 4: relu -> bf16 store + row-sum atomics into csum
template <int MODE>
__global__ __launch_bounds__(512, 2) void gemm8(
    const ushort* __restrict__ Ag, const ushort* __restrict__ Bg, void* __restrict__ Cg,
    int K, long sA, long sB, long sC, int ldc, int colOff,
    float* __restrict__ csum, const float* __restrict__ w0,
    const float* __restrict__ bexp) {
  extern __shared__ ushort lds[];   // [A0 16K | A1 16K | B0 16K | B1 16K] ushorts

  // XCD swizzle: lin%8 = "XCD" (round-robin assumption); each owns (z, y-half)
  const int lin = blockIdx.x + (blockIdx.y << 3) + (blockIdx.z << 6);
  const int xcd = lin & 7, m_ = lin >> 3;
  const int bz = xcd >> 1;
  const int by = ((xcd & 1) << 2) + (m_ >> 3);
  const int bx = m_ & 7;

  const ushort* A  = Ag + (long)bz * sA + (long)(bx << 8) * K;
  const ushort* Bp = Bg + (long)bz * sB + (long)(by << 8) * K;

  const int tid = threadIdx.x;
  // staging: thread covers linear half-tile bytes tid*16; global col pre-swizzled so
  // linear LDS holds the XOR-swizzled layout
  const int sr = tid >> 3;                         // row within half
  const int sc = ((tid & 7) ^ (sr & 7)) << 3;      // ushort col, XOR-swizzled
  const ushort* aS = A + (long)sr * K + sc;
  const ushort* bS = Bp + (long)sr * K + sc;
  const int wOff = (tid >> 6) << 9;                // wave-uniform LDS offset (ushorts)
  ushort* const stA0 = lds + wOff;
  ushort* const stA1 = lds + 16384 + wOff;
  ushort* const stB0 = lds + 32768 + wOff;
  ushort* const stB1 = lds + 49152 + wOff;
  const ushort* const TA0 = lds;          const ushort* const TA1 = lds + 16384;
  const ushort* const TB0 = lds + 32768;  const ushort* const TB1 = lds + 49152;

  auto stg = [&](ushort* base, const ushort* src, int T, int H) {
    stage_half(base + (H << 13), src + (long)(H << 7) * K + ((long)T << 6), K);
  };

  // fragment read offsets (swizzled)
  const int L = tid & 63, wid = tid >> 6;
  const int wr = wid >> 2, wc = wid & 3;
  const int fr = L & 15, g = L >> 4;
  const int off0 = ((g ^ (fr & 7)) << 3);
  const int aO0 = ((wr << 7) + fr) * 64 + off0, aO1 = aO0 ^ 32;
  const int bO0 = ((wc << 6) + fr) * 64 + off0, bO1 = bO0 ^ 32;

  f32x4 acc[8][4] = {};
  bf16x8 af[2][2], bf[4][2];

  const int NT = K >> 6, NTI = NT >> 1;

  // prologue: tile0 -> buf0 (8 loads), B(tile1) -> buf1 (4), A1h0(tile1) (2) = 14 issues
  stg(stB0, bS, 0, 0); stg(stB0, bS, 0, 1); stg(stA0, aS, 0, 0); stg(stA0, aS, 0, 1);
  stg(stB1, bS, 1, 0); stg(stB1, bS, 1, 1);
  stg(stA1, aS, 1, 0);
  asm volatile("s_waitcnt vmcnt(6)" ::: "memory");   // tile0 fully landed
  SBAR;
  // pre-reads for ph1 (B buf0 + A m0-1)
  rd_b8(TB0, bO0, bO1, bf);
  rd_a<0>(TA0, aO0, aO1, af);

  for (int it = 0; it < NTI; ++it) {
    const int t1 = 2 * it + 1, t2 = 2 * it + 2, t3 = 2 * it + 3;
    const bool more = (it + 1 < NTI);

    // ---- ph1: MFMA m0-1 (buf0) ----
    stg(stA1, aS, t1, 1);                 // A1h1(T1)
    PRIO1; mfma16<0>(af, bf, acc); PRIO0;
    rd_a<2>(TA0, aO0, aO1, af);
    SBAR;
    // ---- ph2: MFMA m2-3 ----
    if (more) stg(stB0, bS, t2, 0);       // B0h0(T2)
    PRIO1; mfma16<2>(af, bf, acc); PRIO0;
    rd_a<4>(TA0, aO0, aO1, af);
    SBAR;
    // ---- ph3: MFMA m4-5 ----
    if (more) stg(stB0, bS, t2, 1);       // B0h1(T2)
    PRIO1; mfma16<4>(af, bf, acc); PRIO0;
    rd_a<6>(TA0, aO0, aO1, af);
    SBAR;
    // ---- ph4: MFMA m6-7; then switch to buf1 reads ----
    if (more) { W_VM4; } else { W_VM0; }  // force tile T1 (buf1) landed
    SBAR;                                 // all waves' T1 slices visible
    PRIO1; mfma16<6>(af, bf, acc); PRIO0;
    rd_b8(TB1, bO0, bO1, bf);
    rd_a<0>(TA1, aO0, aO1, af);
    SBAR;
    // ---- ph5: MFMA m0-1 (buf1) ----
    if (more) stg(stA0, aS, t2, 0);       // A0h0(T2)
    PRIO1; mfma16<0>(af, bf, acc); PRIO0;
    rd_a<2>(TA1, aO0, aO1, af);
    SBAR;
    // ---- ph6: MFMA m2-3 ----
    if (more) stg(stA0, aS, t2, 1);       // A0h1(T2)
    PRIO1; mfma16<2>(af, bf, acc); PRIO0;
    rd_a<4>(TA1, aO0, aO1, af);
    SBAR;
    // ---- ph7: MFMA m4-5 ----
    if (more) stg(stB1, bS, t3, 0);       // B1h0(T3)
    PRIO1; mfma16<4>(af, bf, acc); PRIO0;
    rd_a<6>(TA1, aO0, aO1, af);
    SBAR;
    // ---- ph8: MFMA m6-7; then switch to buf0 (tile T2) reads ----
    if (more) stg(stB1, bS, t3, 1);       // B1h1(T3)
    if (more) { W_VM4; }                  // force tile T2 (buf0) landed
    SBAR;
    PRIO1; mfma16<6>(af, bf, acc); PRIO0;
    if (more) {
      rd_b8(TB0, bO0, bO1, bf);
      rd_a<0>(TA0, aO0, aO1, af);
      stg(stA1, aS, t3, 0);               // A1h0(T3) — extra lead for next iter's ph4
    }
    SBAR;
  }

  // ---------------- vectorized epilogue (per-wave private LDS patch) ----------------
  const int cq = fr;                      // fragment col within 16x16 quad
  const int rowB0 = (bx << 8) + (wr << 7);
  const int colB0 = (by << 8) + (wc << 6);

  if (MODE == 3) {
    // per-wave 16x64 fp32 patch, pitch 68 floats (272B rows, 16B-aligned)
    float* eT = (float*)lds + (size_t)wid * 1088;
    float* Cb = (float*)Cg + (long)bz * sC;
    const int er = L >> 4, ec = L & 15;
    #pragma unroll
    for (int m = 0; m < 8; m++) {
      #pragma unroll
      for (int j = 0; j < 4; j++)
        #pragma unroll
        for (int r = 0; r < 4; r++)
          eT[(g * 4 + r) * 68 + j * 16 + cq] = acc[m][j][r];
      #pragma unroll
      for (int q = 0; q < 4; q++) {
        const f32x4 v = *(const f32x4*)&eT[(er + q * 4) * 68 + ec * 4];
        const long row = rowB0 + m * 16 + er + q * 4;
        *(f32x4*)&Cb[row * ldc + colB0 + ec * 4] = v;   // 16 lanes x 16B = 256B/row
      }
    }
  } else {
    // per-wave 16x64 bf16 patch, pitch 72 ushorts (144B rows, 16B-aligned)
    ushort* eT = lds + (size_t)wid * 1152;
    ushort* Cb = (ushort*)Cg + (long)bz * sC;
    const int er = L >> 3, ec = L & 7;
    float w0v[4], bev[4];
    if (MODE == 2) {
      #pragma unroll
      for (int j = 0; j < 4; j++) {
        w0v[j] = w0[colB0 + j * 16 + cq];
        bev[j] = bexp[colB0 + j * 16 + cq];
      }
    }
    #pragma unroll
    for (int m = 0; m < 8; m++) {
      float rsr[4] = {0.f, 0.f, 0.f, 0.f};
      #pragma unroll
      for (int j = 0; j < 4; j++)
        #pragma unroll
        for (int r = 0; r < 4; r++) {
          float x = acc[m][j][r];
          if (MODE == 2) {
            const float cv = csum[(long)bz * N_ + rowB0 + m * 16 + g * 4 + r];
            x = x + cv * w0v[j] + bev[j];
            x = fmaxf(x, 0.f) + log1pf(expf(-fabsf(x)));
          }
          if (MODE == 4) {
            x = fmaxf(x, 0.f);
            rsr[r] += x;
          }
          eT[(g * 4 + r) * 72 + j * 16 + cq] = f2bf(x);
        }
      if (MODE == 4) {
        // reduce across 16 fr-lanes (same g) -> wave's 64-col partial row sum
        #pragma unroll
        for (int r = 0; r < 4; r++) {
          float s = rsr[r];
          s += __shfl_xor(s, 1); s += __shfl_xor(s, 2);
          s += __shfl_xor(s, 4); s += __shfl_xor(s, 8);
          if (fr == 0)
            atomicAdd(&csum[(long)bz * N_ + rowB0 + m * 16 + g * 4 + r], s);
        }
      }
      #pragma unroll
      for (int q = 0; q < 2; q++) {
        const uint4 v = *(const uint4*)&eT[(er + q * 8) * 72 + ec * 8];
        const long row = rowB0 + m * 16 + er + q * 8;
        *(uint4*)&Cb[row * ldc + colOff + colB0 + ec * 8] = v;  // 8 lanes x 16B = 128B/row
      }
    }
  }
}

// ---------------- launch ----------------
extern "C" void kernel_launch(void* const* d_in, const int* in_sizes, int n_in,
                              void* d_out, int out_size, void* d_ws, size_t ws_size,
                              hipStream_t stream) {
  const float* data    = (const float*)d_in[0];
  const float* W_exp   = (const float*)d_in[1];
  const float* b_exp   = (const float*)d_in[2];
  const float* W_merge = (const float*)d_in[3];

  char* ws = (char*)d_ws;
  const size_t MB = 1024 * 1024;
  ushort* cnv  = (ushort*)(ws);             // 32MB: cn, then reused as v_out
  ushort* sim  = (ushort*)(ws + 32 * MB);   // 32MB
  ushort* pe   = (ushort*)(ws + 64 * MB);   // 8MB
  ushort* weT  = (ushort*)(ws + 72 * MB);   // 8MB:  W_exp[1:,:]^T
  ushort* wmT  = (ushort*)(ws + 80 * MB);   // 16MB: W_merge^T
  ushort* catA = (ushort*)(ws + 96 * MB);   // 64MB: [data | counter] bf16
  float*  csum = (float*)(ws + 160 * MB);   // 128KB

  static bool attrs_set = false;
  if (!attrs_set) {
    (void)hipFuncSetAttribute((const void*)gemm8<1>, hipFuncAttributeMaxDynamicSharedMemorySize, 131072);
    (void)hipFuncSetAttribute((const void*)gemm8<2>, hipFuncAttributeMaxDynamicSharedMemorySize, 131072);
    (void)hipFuncSetAttribute((const void*)gemm8<3>, hipFuncAttributeMaxDynamicSharedMemorySize, 131072);
    (void)hipFuncSetAttribute((const void*)gemm8<4>, hipFuncAttributeMaxDynamicSharedMemorySize, 131072);
    attrs_set = true;
  }

  hipMemsetAsync(csum, 0, (size_t)B_ * N_ * sizeof(float), stream);
  prep_all<<<PREP_BLOCKS, 256, 0, stream>>>(data, cnv, catA, pe, W_exp, weT, W_merge, wmT);

  dim3 g8(N_ / 256, N_ / 256, B_);
  // G1: sim = relu(cn cn^T) full grid (NT: B operand = cn rows), row-sums -> csum
  gemm8<4><<<g8, 512, 131072, stream>>>(cnv, cnv, sim, N_, (long)N_ * D_, (long)N_ * D_,
                                        (long)N_ * N_, N_, 0, csum, nullptr, nullptr);
  // G2: v_out = pe @ sim  (sim symmetric -> NT form), into cnv region (cn is dead)
  gemm8<1><<<g8, 512, 131072, stream>>>(pe, sim, cnv, N_, 0, (long)N_ * N_,
                                        (long)N_ * N_, N_, 0, nullptr, nullptr, nullptr);
  // G3: catA[:, D:] = softplus(v_out @ W_exp[1:] + csum*w0 + b_exp)
  gemm8<2><<<g8, 512, 131072, stream>>>(cnv, weT, catA, N_, (long)N_ * N_, 0,
                                        (long)N_ * 2 * D_, 2 * D_, D_, csum, W_exp, b_exp);
  // G4: out = catA @ W_merge
  gemm8<3><<<g8, 512, 131072, stream>>>(catA, wmT, d_out, 2 * D_, (long)N_ * 2 * D_, 0,
                                        (long)N_ * D_, D_, 0, nullptr, nullptr, nullptr);
}